// Round 1
// baseline (2159.762 us; speedup 1.0000x reference)
//
#include <hip/hip_runtime.h>
#include <hip/hip_bf16.h>

// Problem constants (match reference)
#define B_ 2
#define T_ 2048
#define D_ 2048
#define H_ 16
#define G_ 4
#define HD_ 128
#define GS_ (H_/G_)

typedef _Float16 half8 __attribute__((ext_vector_type(8)));
typedef float f32x4 __attribute__((ext_vector_type(4)));

// ---------------- fp32 -> fp16 conversion ----------------
__global__ void cvt_f16(const float* __restrict__ in, _Float16* __restrict__ out, int n) {
    int i = blockIdx.x * blockDim.x + threadIdx.x;
    int stride = blockDim.x * gridDim.x;
    for (; i < n; i += stride) out[i] = (_Float16)in[i];
}

// ---------------- RoPE tables: cos/sin (T_, 64) ----------------
// emb = concat([freqs, freqs]) so table for i>=64 repeats i-64; store only 64.
__global__ void rope_tables_k(float* __restrict__ cosT, float* __restrict__ sinT) {
    int i = blockIdx.x * blockDim.x + threadIdx.x; // T_*64 threads
    int t = i >> 6, l = i & 63;
    float inv_freq = powf(10000.0f, -((float)(2 * l)) / 128.0f);
    float a = (float)t * inv_freq;
    cosT[i] = cosf(a);
    sinT[i] = sinf(a);
}

// ---------------- TN GEMM: C[M,N] = A[M,K] * B[N,K]^T (f16 in, f32 out) ----------------
// Per-wave 32x64 output tile: 2 (M) x 4 (N) MFMA 16x16 subtiles, K-step 32.
// A-frag: lane holds A[row = l&15][k0 + (l>>4)*8 + j], j=0..7  (one 16B load)
// B-frag: lane holds B^T... i.e. W[col = l&15][k0 + (l>>4)*8 + j] (same pattern)
// C/D: col = lane&15, row = (lane>>4)*4 + r   [guide-verified, dtype-independent]
__global__ void gemm_tn_f16(const _Float16* __restrict__ A,
                            const _Float16* __restrict__ Bm,
                            float* __restrict__ C,
                            int M, int N, int Kd) {
    int wave = (int)((blockIdx.x * (size_t)blockDim.x + threadIdx.x) >> 6);
    int lane = threadIdx.x & 63;
    int ntiles = N >> 6;                 // 64-col tiles
    int wm = wave / ntiles;
    int wn = wave - wm * ntiles;
    if (wm * 32 >= M) return;
    int l15 = lane & 15;
    int klo = (lane >> 4) * 8;
    const _Float16* ap = A + (size_t)(wm * 32 + l15) * Kd + klo;
    const _Float16* bp = Bm + (size_t)(wn * 64 + l15) * Kd + klo;
    size_t kstep16 = (size_t)16 * Kd;

    f32x4 acc[2][4];
    #pragma unroll
    for (int i = 0; i < 2; i++)
        #pragma unroll
        for (int j = 0; j < 4; j++) acc[i][j] = (f32x4){0.f, 0.f, 0.f, 0.f};

    for (int k0 = 0; k0 < Kd; k0 += 32) {
        half8 a0 = *(const half8*)(ap + k0);
        half8 a1 = *(const half8*)(ap + kstep16 + k0);
        half8 b0 = *(const half8*)(bp + k0);
        half8 b1 = *(const half8*)(bp + kstep16 + k0);
        half8 b2 = *(const half8*)(bp + 2 * kstep16 + k0);
        half8 b3 = *(const half8*)(bp + 3 * kstep16 + k0);
        acc[0][0] = __builtin_amdgcn_mfma_f32_16x16x32_f16(a0, b0, acc[0][0], 0, 0, 0);
        acc[0][1] = __builtin_amdgcn_mfma_f32_16x16x32_f16(a0, b1, acc[0][1], 0, 0, 0);
        acc[0][2] = __builtin_amdgcn_mfma_f32_16x16x32_f16(a0, b2, acc[0][2], 0, 0, 0);
        acc[0][3] = __builtin_amdgcn_mfma_f32_16x16x32_f16(a0, b3, acc[0][3], 0, 0, 0);
        acc[1][0] = __builtin_amdgcn_mfma_f32_16x16x32_f16(a1, b0, acc[1][0], 0, 0, 0);
        acc[1][1] = __builtin_amdgcn_mfma_f32_16x16x32_f16(a1, b1, acc[1][1], 0, 0, 0);
        acc[1][2] = __builtin_amdgcn_mfma_f32_16x16x32_f16(a1, b2, acc[1][2], 0, 0, 0);
        acc[1][3] = __builtin_amdgcn_mfma_f32_16x16x32_f16(a1, b3, acc[1][3], 0, 0, 0);
    }

    int rbase = wm * 32 + (lane >> 4) * 4;
    int cbase = wn * 64 + l15;
    #pragma unroll
    for (int mi = 0; mi < 2; mi++)
        #pragma unroll
        for (int ni = 0; ni < 4; ni++)
            #pragma unroll
            for (int r = 0; r < 4; r++)
                C[(size_t)(rbase + mi * 16 + r) * N + cbase + ni * 16] = acc[mi][ni][r];
}

// ---------------- fused RMSNorm + RoPE (in-place, fp32) ----------------
// One wave per 128-elem row. Lane l owns elems l and l+64 (rotate-half pairing in-lane).
__global__ void rmsnorm_rope_k(float* __restrict__ X, const float* __restrict__ w,
                               const float* __restrict__ cosT, const float* __restrict__ sinT,
                               int heads, float outScale) {
    int gw = (int)((blockIdx.x * (size_t)blockDim.x + threadIdx.x) >> 6);
    int lane = threadIdx.x & 63;
    float* row = X + (size_t)gw * HD_;
    int t = (gw / heads) % T_;   // row index = (b*T + t)*heads + h
    float x0 = row[lane];
    float x1 = row[lane + 64];
    float ss = x0 * x0 + x1 * x1;
    #pragma unroll
    for (int off = 1; off < 64; off <<= 1) ss += __shfl_xor(ss, off);
    float inv = rsqrtf(ss * (1.0f / 128.0f) + 1e-6f);
    float n0 = x0 * inv * w[lane];
    float n1 = x1 * inv * w[lane + 64];
    float c = cosT[t * 64 + lane];
    float s = sinT[t * 64 + lane];
    row[lane]      = (n0 * c - n1 * s) * outScale;
    row[lane + 64] = (n1 * c + n0 * s) * outScale;
}

// ---------------- causal GQA flash attention (fp32 VALU baseline) ----------------
// Grid: (T/64, H, B). Block: 256 = 64 q-rows x 4 dim-slices (32 dims each).
// K/V tiles (32 keys x 128 dims) staged in LDS with an 8-word gap per 32-word
// slice (stride 40) so the 4 dp-slices land in different banks.
__global__ void __launch_bounds__(256) attn_k(const float* __restrict__ Q,
                                              const float* __restrict__ Kt,
                                              const float* __restrict__ Vt,
                                              _Float16* __restrict__ ctx) {
    int qb = blockIdx.x, h = blockIdx.y, b = blockIdx.z;
    int g = h >> 2;                     // h / GS_
    int tid = threadIdx.x;
    int ql = tid >> 2, dp = tid & 3;
    int q = qb * 64 + ql;

    __shared__ float sK[32 * 160];
    __shared__ float sV[32 * 160];

    float qreg[32];
    const float* qrow = Q + ((size_t)((b * T_ + q) * H_ + h)) * HD_ + dp * 32;
    #pragma unroll
    for (int i = 0; i < 32; i++) qreg[i] = qrow[i];

    float m = -INFINITY, lsum = 0.f;
    float o[32];
    #pragma unroll
    for (int i = 0; i < 32; i++) o[i] = 0.f;

    int kend = qb * 64 + 64;
    for (int kt = 0; kt < kend; kt += 32) {
        __syncthreads();   // protect previous iteration's LDS reads
        for (int idx = tid; idx < 32 * 128; idx += 256) {
            int kk = idx >> 7, d = idx & 127;
            size_t gidx = ((size_t)((b * T_ + kt + kk) * G_ + g)) * HD_ + d;
            int sidx = kk * 160 + d + 8 * (d >> 5);
            sK[sidx] = Kt[gidx];
            sV[sidx] = Vt[gidx];
        }
        __syncthreads();

        float s[32];
        #pragma unroll
        for (int kk = 0; kk < 32; kk++) {
            const float* kr = &sK[kk * 160 + dp * 40];
            float p = 0.f;
            #pragma unroll
            for (int i4 = 0; i4 < 8; i4++) {
                f32x4 kv = *(const f32x4*)(kr + 4 * i4);
                p += qreg[4 * i4 + 0] * kv[0] + qreg[4 * i4 + 1] * kv[1]
                   + qreg[4 * i4 + 2] * kv[2] + qreg[4 * i4 + 3] * kv[3];
            }
            p += __shfl_xor(p, 1);   // combine the 4 dim-slices (lanes differ in bits 0..1)
            p += __shfl_xor(p, 2);
            s[kk] = (kt + kk <= q) ? p : -INFINITY;
        }

        float tmax = -INFINITY;
        #pragma unroll
        for (int kk = 0; kk < 32; kk++) tmax = fmaxf(tmax, s[kk]);
        float nm = fmaxf(m, tmax);       // finite after tile 0 (key 0 always unmasked)
        float alpha = __expf(m - nm);    // exp(-inf)=0 on first tile
        lsum *= alpha;
        #pragma unroll
        for (int i = 0; i < 32; i++) o[i] *= alpha;

        #pragma unroll
        for (int kk = 0; kk < 32; kk++) {
            float p = __expf(s[kk] - nm);
            lsum += p;
            const float* vr = &sV[kk * 160 + dp * 40];
            #pragma unroll
            for (int i4 = 0; i4 < 8; i4++) {
                f32x4 vv = *(const f32x4*)(vr + 4 * i4);
                o[4 * i4 + 0] += p * vv[0]; o[4 * i4 + 1] += p * vv[1];
                o[4 * i4 + 2] += p * vv[2]; o[4 * i4 + 3] += p * vv[3];
            }
        }
        m = nm;
    }

    float invl = 1.0f / lsum;
    _Float16* orow = ctx + (size_t)(b * T_ + q) * (H_ * HD_) + h * HD_ + dp * 32;
    #pragma unroll
    for (int i = 0; i < 32; i++) orow[i] = (_Float16)(o[i] * invl);
}

// ---------------- launch ----------------
extern "C" void kernel_launch(void* const* d_in, const int* in_sizes, int n_in,
                              void* d_out, int out_size, void* d_ws, size_t ws_size,
                              hipStream_t stream) {
    const float* x   = (const float*)d_in[0];
    const float* Wq  = (const float*)d_in[1];
    const float* Wk  = (const float*)d_in[2];
    const float* Wv  = (const float*)d_in[3];
    const float* Wo  = (const float*)d_in[4];
    const float* qnw = (const float*)d_in[5];
    const float* knw = (const float*)d_in[6];
    float* out = (float*)d_out;

    char* ws = (char*)d_ws;
    size_t off = 0;
    auto alloc = [&](size_t bytes) {
        char* p = ws + off;
        off += (bytes + 255) & ~(size_t)255;
        return p;
    };
    _Float16* x_h  = (_Float16*)alloc((size_t)B_ * T_ * D_ * 2);
    _Float16* wq_h = (_Float16*)alloc((size_t)H_ * HD_ * D_ * 2);
    _Float16* wk_h = (_Float16*)alloc((size_t)G_ * HD_ * D_ * 2);
    _Float16* wv_h = (_Float16*)alloc((size_t)G_ * HD_ * D_ * 2);
    _Float16* wo_h = (_Float16*)alloc((size_t)D_ * H_ * HD_ * 2);
    float* q_f = (float*)alloc((size_t)B_ * T_ * H_ * HD_ * 4);
    float* k_f = (float*)alloc((size_t)B_ * T_ * G_ * HD_ * 4);
    float* v_f = (float*)alloc((size_t)B_ * T_ * G_ * HD_ * 4);
    _Float16* ctx_h = (_Float16*)alloc((size_t)B_ * T_ * H_ * HD_ * 2);
    float* cosT = (float*)alloc((size_t)T_ * 64 * 4);
    float* sinT = (float*)alloc((size_t)T_ * 64 * 4);

    // dtype conversions
    cvt_f16<<<2048, 256, 0, stream>>>(x,  x_h,  B_ * T_ * D_);
    cvt_f16<<<2048, 256, 0, stream>>>(Wq, wq_h, H_ * HD_ * D_);
    cvt_f16<<<1024, 256, 0, stream>>>(Wk, wk_h, G_ * HD_ * D_);
    cvt_f16<<<1024, 256, 0, stream>>>(Wv, wv_h, G_ * HD_ * D_);
    cvt_f16<<<2048, 256, 0, stream>>>(Wo, wo_h, D_ * H_ * HD_);
    rope_tables_k<<<(T_ * 64) / 256, 256, 0, stream>>>(cosT, sinT);

    // QKV projections (TN GEMM)
    // waves = (M/32)*(N/64); 4 waves per block
    gemm_tn_f16<<<(128 * 32) / 4, 256, 0, stream>>>(x_h, wq_h, q_f, B_ * T_, H_ * HD_, D_);
    gemm_tn_f16<<<(128 * 8)  / 4, 256, 0, stream>>>(x_h, wk_h, k_f, B_ * T_, G_ * HD_, D_);
    gemm_tn_f16<<<(128 * 8)  / 4, 256, 0, stream>>>(x_h, wv_h, v_f, B_ * T_, G_ * HD_, D_);

    // norm + rope; fold score scale (1/HD = 1/128) into Q
    rmsnorm_rope_k<<<(B_ * T_ * H_) / 4, 256, 0, stream>>>(q_f, qnw, cosT, sinT, H_, 1.0f / 128.0f);
    rmsnorm_rope_k<<<(B_ * T_ * G_) / 4, 256, 0, stream>>>(k_f, knw, cosT, sinT, G_, 1.0f);

    // causal GQA attention -> ctx (f16)
    attn_k<<<dim3(T_ / 64, H_, B_), 256, 0, stream>>>(q_f, k_f, v_f, ctx_h);

    // output projection -> d_out (fp32)
    gemm_tn_f16<<<(128 * 32) / 4, 256, 0, stream>>>(ctx_h, wo_h, out, B_ * T_, D_, H_ * HD_);
}

// Round 2
// 678.540 us; speedup vs baseline: 3.1830x; 3.1830x over previous
//
#include <hip/hip_runtime.h>
#include <hip/hip_bf16.h>

// Problem constants (match reference)
#define B_ 2
#define T_ 2048
#define D_ 2048
#define H_ 16
#define G_ 4
#define HD_ 128
#define GS_ (H_/G_)

typedef _Float16 half8 __attribute__((ext_vector_type(8)));
typedef _Float16 half2_t __attribute__((ext_vector_type(2)));
typedef float f32x4 __attribute__((ext_vector_type(4)));

// ---------------- fp32 -> fp16 conversion ----------------
__global__ void cvt_f16(const float* __restrict__ in, _Float16* __restrict__ out, int n) {
    int i = blockIdx.x * blockDim.x + threadIdx.x;
    int stride = blockDim.x * gridDim.x;
    for (; i < n; i += stride) out[i] = (_Float16)in[i];
}

// ---------------- RoPE tables: cos/sin (T_, 64) ----------------
__global__ void rope_tables_k(float* __restrict__ cosT, float* __restrict__ sinT) {
    int i = blockIdx.x * blockDim.x + threadIdx.x; // T_*64 threads
    int t = i >> 6, l = i & 63;
    float inv_freq = powf(10000.0f, -((float)(2 * l)) / 128.0f);
    float a = (float)t * inv_freq;
    cosT[i] = cosf(a);
    sinT[i] = sinf(a);
}

// ---------------- TN GEMM: C[M,N] = A[M,K] * B[N,K]^T (f16 in, f32 out) ----------------
__global__ void gemm_tn_f16(const _Float16* __restrict__ A,
                            const _Float16* __restrict__ Bm,
                            float* __restrict__ C,
                            int M, int N, int Kd) {
    int wave = (int)((blockIdx.x * (size_t)blockDim.x + threadIdx.x) >> 6);
    int lane = threadIdx.x & 63;
    int ntiles = N >> 6;                 // 64-col tiles
    int wm = wave / ntiles;
    int wn = wave - wm * ntiles;
    if (wm * 32 >= M) return;
    int l15 = lane & 15;
    int klo = (lane >> 4) * 8;
    const _Float16* ap = A + (size_t)(wm * 32 + l15) * Kd + klo;
    const _Float16* bp = Bm + (size_t)(wn * 64 + l15) * Kd + klo;
    size_t kstep16 = (size_t)16 * Kd;

    f32x4 acc[2][4];
    #pragma unroll
    for (int i = 0; i < 2; i++)
        #pragma unroll
        for (int j = 0; j < 4; j++) acc[i][j] = (f32x4){0.f, 0.f, 0.f, 0.f};

    for (int k0 = 0; k0 < Kd; k0 += 32) {
        half8 a0 = *(const half8*)(ap + k0);
        half8 a1 = *(const half8*)(ap + kstep16 + k0);
        half8 b0 = *(const half8*)(bp + k0);
        half8 b1 = *(const half8*)(bp + kstep16 + k0);
        half8 b2 = *(const half8*)(bp + 2 * kstep16 + k0);
        half8 b3 = *(const half8*)(bp + 3 * kstep16 + k0);
        acc[0][0] = __builtin_amdgcn_mfma_f32_16x16x32_f16(a0, b0, acc[0][0], 0, 0, 0);
        acc[0][1] = __builtin_amdgcn_mfma_f32_16x16x32_f16(a0, b1, acc[0][1], 0, 0, 0);
        acc[0][2] = __builtin_amdgcn_mfma_f32_16x16x32_f16(a0, b2, acc[0][2], 0, 0, 0);
        acc[0][3] = __builtin_amdgcn_mfma_f32_16x16x32_f16(a0, b3, acc[0][3], 0, 0, 0);
        acc[1][0] = __builtin_amdgcn_mfma_f32_16x16x32_f16(a1, b0, acc[1][0], 0, 0, 0);
        acc[1][1] = __builtin_amdgcn_mfma_f32_16x16x32_f16(a1, b1, acc[1][1], 0, 0, 0);
        acc[1][2] = __builtin_amdgcn_mfma_f32_16x16x32_f16(a1, b2, acc[1][2], 0, 0, 0);
        acc[1][3] = __builtin_amdgcn_mfma_f32_16x16x32_f16(a1, b3, acc[1][3], 0, 0, 0);
    }

    int rbase = wm * 32 + (lane >> 4) * 4;
    int cbase = wn * 64 + l15;
    #pragma unroll
    for (int mi = 0; mi < 2; mi++)
        #pragma unroll
        for (int ni = 0; ni < 4; ni++)
            #pragma unroll
            for (int r = 0; r < 4; r++)
                C[(size_t)(rbase + mi * 16 + r) * N + cbase + ni * 16] = acc[mi][ni][r];
}

// ---------------- fused RMSNorm + RoPE (in-place, fp32) ----------------
__global__ void rmsnorm_rope_k(float* __restrict__ X, const float* __restrict__ w,
                               const float* __restrict__ cosT, const float* __restrict__ sinT,
                               int heads, float outScale) {
    int gw = (int)((blockIdx.x * (size_t)blockDim.x + threadIdx.x) >> 6);
    int lane = threadIdx.x & 63;
    float* row = X + (size_t)gw * HD_;
    int t = (gw / heads) % T_;   // row index = (b*T + t)*heads + h
    float x0 = row[lane];
    float x1 = row[lane + 64];
    float ss = x0 * x0 + x1 * x1;
    #pragma unroll
    for (int off = 1; off < 64; off <<= 1) ss += __shfl_xor(ss, off);
    float inv = rsqrtf(ss * (1.0f / 128.0f) + 1e-6f);
    float n0 = x0 * inv * w[lane];
    float n1 = x1 * inv * w[lane + 64];
    float c = cosT[t * 64 + lane];
    float s = sinT[t * 64 + lane];
    row[lane]      = (n0 * c - n1 * s) * outScale;
    row[lane + 64] = (n1 * c + n0 * s) * outScale;
}

// ---------------- causal GQA flash attention (MFMA) ----------------
// Grid: (T/64, H, B). Block: 256 = 4 waves; wave w owns q-rows [qb*64+w*16, +16).
// Per 32-key tile: S^T = mfma(Kfrag, Qfrag) (8 MFMA), in-lane softmax (8 vals/lane,
// cross-lane reduce via shfl_xor 16/32), P -> per-wave LDS -> A-frag, PV (8 MFMA).
// sK: [32][136] f16 (pad 8 -> bank-even b128 reads).
// sVT: V transposed [128][40] f16 with 16B-granule XOR swizzle (key (d>>4)&3) so the
//      b16 transpose-writes spread banks; reads stay bank-even.
__global__ void __launch_bounds__(256) attn_mfma(const float* __restrict__ Q,
                                                 const float* __restrict__ Kt,
                                                 const float* __restrict__ Vt,
                                                 _Float16* __restrict__ ctx) {
    int qb = blockIdx.x, h = blockIdx.y, b = blockIdx.z;
    int g = h >> 2;
    int tid = threadIdx.x;
    int w = tid >> 6, lane = tid & 63;
    int l15 = lane & 15, g4 = lane >> 4;

    __shared__ _Float16 sK[32 * 136];
    __shared__ _Float16 sVT[128 * 40];
    __shared__ _Float16 sP[4 * 16 * 40];

    int qbase = qb * 64 + w * 16;
    int qg = qbase + l15;

    // Q fragments (B-operand: col = l15 = q row, k = g4*8 + step*32 + j)
    half8 qfrag[4];
    {
        const float* qrow = Q + ((size_t)((b * T_ + qbase + l15) * H_ + h)) * HD_ + g4 * 8;
        #pragma unroll
        for (int st = 0; st < 4; st++)
            #pragma unroll
            for (int j = 0; j < 8; j++) qfrag[st][j] = (_Float16)qrow[st * 32 + j];
    }

    f32x4 o[8];
    #pragma unroll
    for (int i = 0; i < 8; i++) o[i] = (f32x4){0.f, 0.f, 0.f, 0.f};
    float m = -INFINITY, lsum = 0.f;

    int row = tid >> 3, seg = tid & 7;      // staging: row = key 0..31, seg = 16-dim chunk
    int kend = qb * 64 + 64;
    int wkend = qbase + 16;                  // this wave's causal frontier

    for (int kt = 0; kt < kend; kt += 32) {
        __syncthreads();                     // previous tile's LDS reads done
        {
            size_t gbase = ((size_t)((b * T_ + kt + row) * G_ + g)) * HD_ + seg * 16;
            const float* kg_ = Kt + gbase;
            const float* vg_ = Vt + gbase;
            half8 h0, h1;
            #pragma unroll
            for (int j = 0; j < 8; j++) { h0[j] = (_Float16)kg_[j]; h1[j] = (_Float16)kg_[8 + j]; }
            *(half8*)&sK[row * 136 + seg * 16] = h0;
            *(half8*)&sK[row * 136 + seg * 16 + 8] = h1;
            // V transpose: sVT[d][k], granule-swizzled by (d>>4)&3 = seg&3
            #pragma unroll
            for (int j = 0; j < 16; j++) {
                int d = seg * 16 + j;
                int idx = d * 40 + (((row >> 3) ^ (seg & 3)) << 3) + (row & 7);
                sVT[idx] = (_Float16)vg_[j];
            }
        }
        __syncthreads();

        if (kt < wkend) {
            // S^T = K * Q^T : lane holds S[k = kt + 16*sub + 4*g4 + r][q = qg]
            f32x4 stc[2];
            stc[0] = (f32x4){0.f, 0.f, 0.f, 0.f};
            stc[1] = (f32x4){0.f, 0.f, 0.f, 0.f};
            #pragma unroll
            for (int st = 0; st < 4; st++) {
                half8 kf0 = *(const half8*)&sK[l15 * 136 + g4 * 8 + st * 32];
                half8 kf1 = *(const half8*)&sK[(l15 + 16) * 136 + g4 * 8 + st * 32];
                stc[0] = __builtin_amdgcn_mfma_f32_16x16x32_f16(kf0, qfrag[st], stc[0], 0, 0, 0);
                stc[1] = __builtin_amdgcn_mfma_f32_16x16x32_f16(kf1, qfrag[st], stc[1], 0, 0, 0);
            }
            // causal mask
            float sv[8];
            #pragma unroll
            for (int sub = 0; sub < 2; sub++)
                #pragma unroll
                for (int r = 0; r < 4; r++) {
                    int kgi = kt + 16 * sub + 4 * g4 + r;
                    sv[sub * 4 + r] = (kgi <= qg) ? stc[sub][r] : -INFINITY;
                }
            // online softmax over k for column q = l15 (+xor16/32 lane groups)
            float tmax = sv[0];
            #pragma unroll
            for (int i = 1; i < 8; i++) tmax = fmaxf(tmax, sv[i]);
            tmax = fmaxf(tmax, __shfl_xor(tmax, 16));
            tmax = fmaxf(tmax, __shfl_xor(tmax, 32));
            float nm = fmaxf(m, tmax);
            float alpha = __expf(m - nm);    // first tile: exp(-inf)=0
            float p[8], rsum = 0.f;
            #pragma unroll
            for (int i = 0; i < 8; i++) { p[i] = __expf(sv[i] - nm); rsum += p[i]; }
            rsum += __shfl_xor(rsum, 16);
            rsum += __shfl_xor(rsum, 32);
            lsum = lsum * alpha + rsum;
            m = nm;
            // rescale O (O's q index = 4*g4 + r; alpha lives at lane q = l15)
            #pragma unroll
            for (int r = 0; r < 4; r++) {
                float ar = __shfl(alpha, 4 * g4 + r);
                #pragma unroll
                for (int d = 0; d < 8; d++) o[d][r] *= ar;
            }
            // P -> LDS: sP[w][q = l15][k' = 16*sub + 4*g4 + r] as half2 pairs
            _Float16* pw = &sP[w * 640];
            #pragma unroll
            for (int sub = 0; sub < 2; sub++)
                #pragma unroll
                for (int rp = 0; rp < 4; rp += 2) {
                    half2_t hp;
                    hp[0] = (_Float16)p[sub * 4 + rp];
                    hp[1] = (_Float16)p[sub * 4 + rp + 1];
                    *(half2_t*)&pw[l15 * 40 + 16 * sub + 4 * g4 + rp] = hp;
                }
            asm volatile("s_waitcnt lgkmcnt(0)" ::: "memory");
            __builtin_amdgcn_sched_barrier(0);
            // PV: O[q][d] += P[16x32] * V^T ; A-frag: P[row=l15][k=8*g4+j]
            half8 pf = *(const half8*)&pw[l15 * 40 + g4 * 8];
            #pragma unroll
            for (int d = 0; d < 8; d++) {
                int vrow = l15 + 16 * d;
                half8 vf = *(const half8*)&sVT[vrow * 40 + ((g4 ^ (d & 3)) << 3)];
                o[d] = __builtin_amdgcn_mfma_f32_16x16x32_f16(pf, vf, o[d], 0, 0, 0);
            }
        }
    }

    // epilogue: O's q = 4*g4 + r; 1/lsum lives at lane q = l15
    float invl = 1.0f / lsum;
    #pragma unroll
    for (int r = 0; r < 4; r++) {
        float ir = __shfl(invl, 4 * g4 + r);
        _Float16* orow = ctx + (size_t)(b * T_ + qbase + 4 * g4 + r) * (H_ * HD_) + h * HD_ + l15;
        #pragma unroll
        for (int d = 0; d < 8; d++) orow[d * 16] = (_Float16)(o[d][r] * ir);
    }
}

// ---------------- launch ----------------
extern "C" void kernel_launch(void* const* d_in, const int* in_sizes, int n_in,
                              void* d_out, int out_size, void* d_ws, size_t ws_size,
                              hipStream_t stream) {
    const float* x   = (const float*)d_in[0];
    const float* Wq  = (const float*)d_in[1];
    const float* Wk  = (const float*)d_in[2];
    const float* Wv  = (const float*)d_in[3];
    const float* Wo  = (const float*)d_in[4];
    const float* qnw = (const float*)d_in[5];
    const float* knw = (const float*)d_in[6];
    float* out = (float*)d_out;

    char* ws = (char*)d_ws;
    size_t off = 0;
    auto alloc = [&](size_t bytes) {
        char* p = ws + off;
        off += (bytes + 255) & ~(size_t)255;
        return p;
    };
    _Float16* x_h  = (_Float16*)alloc((size_t)B_ * T_ * D_ * 2);
    _Float16* wq_h = (_Float16*)alloc((size_t)H_ * HD_ * D_ * 2);
    _Float16* wk_h = (_Float16*)alloc((size_t)G_ * HD_ * D_ * 2);
    _Float16* wv_h = (_Float16*)alloc((size_t)G_ * HD_ * D_ * 2);
    _Float16* wo_h = (_Float16*)alloc((size_t)D_ * H_ * HD_ * 2);
    float* q_f = (float*)alloc((size_t)B_ * T_ * H_ * HD_ * 4);
    float* k_f = (float*)alloc((size_t)B_ * T_ * G_ * HD_ * 4);
    float* v_f = (float*)alloc((size_t)B_ * T_ * G_ * HD_ * 4);
    _Float16* ctx_h = (_Float16*)alloc((size_t)B_ * T_ * H_ * HD_ * 2);
    float* cosT = (float*)alloc((size_t)T_ * 64 * 4);
    float* sinT = (float*)alloc((size_t)T_ * 64 * 4);

    // dtype conversions
    cvt_f16<<<2048, 256, 0, stream>>>(x,  x_h,  B_ * T_ * D_);
    cvt_f16<<<2048, 256, 0, stream>>>(Wq, wq_h, H_ * HD_ * D_);
    cvt_f16<<<1024, 256, 0, stream>>>(Wk, wk_h, G_ * HD_ * D_);
    cvt_f16<<<1024, 256, 0, stream>>>(Wv, wv_h, G_ * HD_ * D_);
    cvt_f16<<<2048, 256, 0, stream>>>(Wo, wo_h, D_ * H_ * HD_);
    rope_tables_k<<<(T_ * 64) / 256, 256, 0, stream>>>(cosT, sinT);

    // QKV projections (TN GEMM)
    gemm_tn_f16<<<(128 * 32) / 4, 256, 0, stream>>>(x_h, wq_h, q_f, B_ * T_, H_ * HD_, D_);
    gemm_tn_f16<<<(128 * 8)  / 4, 256, 0, stream>>>(x_h, wk_h, k_f, B_ * T_, G_ * HD_, D_);
    gemm_tn_f16<<<(128 * 8)  / 4, 256, 0, stream>>>(x_h, wv_h, v_f, B_ * T_, G_ * HD_, D_);

    // norm + rope; fold score scale (1/HD = 1/128) into Q
    rmsnorm_rope_k<<<(B_ * T_ * H_) / 4, 256, 0, stream>>>(q_f, qnw, cosT, sinT, H_, 1.0f / 128.0f);
    rmsnorm_rope_k<<<(B_ * T_ * G_) / 4, 256, 0, stream>>>(k_f, knw, cosT, sinT, G_, 1.0f);

    // causal GQA attention -> ctx (f16)
    attn_mfma<<<dim3(T_ / 64, H_, B_), 256, 0, stream>>>(q_f, k_f, v_f, ctx_h);

    // output projection -> d_out (fp32)
    gemm_tn_f16<<<(128 * 32) / 4, 256, 0, stream>>>(ctx_h, wo_h, out, B_ * T_, D_, H_ * HD_);
}

// Round 3
// 378.801 us; speedup vs baseline: 5.7016x; 1.7913x over previous
//
#include <hip/hip_runtime.h>
#include <hip/hip_bf16.h>

// Problem constants (match reference)
#define B_ 2
#define T_ 2048
#define D_ 2048
#define H_ 16
#define G_ 4
#define HD_ 128
#define GS_ (H_/G_)

typedef _Float16 half8 __attribute__((ext_vector_type(8)));
typedef _Float16 half2_t __attribute__((ext_vector_type(2)));
typedef float f32x4 __attribute__((ext_vector_type(4)));

// ---------------- fp32 -> fp16 conversion ----------------
__global__ void cvt_f16(const float* __restrict__ in, _Float16* __restrict__ out, int n) {
    int i = blockIdx.x * blockDim.x + threadIdx.x;
    int stride = blockDim.x * gridDim.x;
    for (; i < n; i += stride) out[i] = (_Float16)in[i];
}

// ---------------- RoPE tables: cos/sin (T_, 64) ----------------
__global__ void rope_tables_k(float* __restrict__ cosT, float* __restrict__ sinT) {
    int i = blockIdx.x * blockDim.x + threadIdx.x; // T_*64 threads
    int t = i >> 6, l = i & 63;
    float inv_freq = powf(10000.0f, -((float)(2 * l)) / 128.0f);
    float a = (float)t * inv_freq;
    cosT[i] = cosf(a);
    sinT[i] = sinf(a);
}

// ---------------- Tiled TN GEMM (m97 structure) ----------------
// C[M,N] = A[M,K] * B[N,K]^T, f16 in / f32 out.
// Block: 256 threads = 4 waves, 128x128 output tile, BK=32.
// Wave w = (wm,wn) computes 64x64: acc[4][4] of 16x16x32 MFMA.
// LDS tiles sA/sB: [128][32] f16 linear (row-major) — matches global_load_lds
// linear lane order: slot s (16B) = (row = s>>2, kchunk = s&3).
// Dual-output support (fused K/V proj): blockIdx.y < n0t -> (B0,C0) else (B1,C1).
__global__ void __launch_bounds__(256) gemm_tile(const _Float16* __restrict__ A,
                                                 const _Float16* __restrict__ B0,
                                                 float* __restrict__ C0, int n0t,
                                                 const _Float16* __restrict__ B1,
                                                 float* __restrict__ C1, int n1t,
                                                 int Kd) {
    __shared__ _Float16 sA[128 * 32];
    __shared__ _Float16 sB[128 * 32];

    int tid = threadIdx.x;
    int w = tid >> 6, lane = tid & 63;
    int l15 = lane & 15, g4 = lane >> 4;
    int wm = w >> 1, wn = w & 1;

    const _Float16* Bsel;
    float* Csel;
    int ldc, cb;
    if ((int)blockIdx.y < n0t) { Bsel = B0; Csel = C0; ldc = n0t * 128; cb = blockIdx.y; }
    else                       { Bsel = B1; Csel = C1; ldc = n1t * 128; cb = blockIdx.y - n0t; }

    const _Float16* Ab = A + (size_t)(blockIdx.x * 128) * Kd;
    const _Float16* Bb = Bsel + (size_t)(cb * 128) * Kd;

    // staging geometry: this wave's two 1024B instructions per tile
    int s0 = w * 128 + lane;          // slot index 0..511 (16B granules)
    int s1 = s0 + 64;
    int r0 = s0 >> 2, c0 = s0 & 3;
    int r1 = s1 >> 2, c1 = s1 & 3;
    size_t ga0 = (size_t)r0 * Kd + c0 * 8;
    size_t ga1 = (size_t)r1 * Kd + c1 * 8;
    _Float16* lds_a0 = sA + (size_t)(w * 2) * 512;
    _Float16* lds_a1 = sA + (size_t)(w * 2 + 1) * 512;
    _Float16* lds_b0 = sB + (size_t)(w * 2) * 512;
    _Float16* lds_b1 = sB + (size_t)(w * 2 + 1) * 512;

    #define STAGE(K0)                                                                     \
        do {                                                                              \
            __builtin_amdgcn_global_load_lds(                                             \
                (const __attribute__((address_space(1))) unsigned int*)(Ab + ga0 + (K0)), \
                (__attribute__((address_space(3))) unsigned int*)lds_a0, 16, 0, 0);       \
            __builtin_amdgcn_global_load_lds(                                             \
                (const __attribute__((address_space(1))) unsigned int*)(Ab + ga1 + (K0)), \
                (__attribute__((address_space(3))) unsigned int*)lds_a1, 16, 0, 0);       \
            __builtin_amdgcn_global_load_lds(                                             \
                (const __attribute__((address_space(1))) unsigned int*)(Bb + ga0 + (K0)), \
                (__attribute__((address_space(3))) unsigned int*)lds_b0, 16, 0, 0);       \
            __builtin_amdgcn_global_load_lds(                                             \
                (const __attribute__((address_space(1))) unsigned int*)(Bb + ga1 + (K0)), \
                (__attribute__((address_space(3))) unsigned int*)lds_b1, 16, 0, 0);       \
        } while (0)

    f32x4 acc[4][4];
    #pragma unroll
    for (int i = 0; i < 4; i++)
        #pragma unroll
        for (int j = 0; j < 4; j++) acc[i][j] = (f32x4){0.f, 0.f, 0.f, 0.f};

    STAGE(0);

    int nIt = Kd >> 5;
    for (int it = 0; it < nIt; ++it) {
        __syncthreads();   // staging of this tile complete (compiler drains vmcnt)

        half8 af[4], bf[4];
        #pragma unroll
        for (int mi = 0; mi < 4; mi++)
            af[mi] = *(const half8*)&sA[(wm * 64 + mi * 16 + l15) * 32 + g4 * 8];
        #pragma unroll
        for (int ni = 0; ni < 4; ni++)
            bf[ni] = *(const half8*)&sB[(wn * 64 + ni * 16 + l15) * 32 + g4 * 8];

        #pragma unroll
        for (int mi = 0; mi < 4; mi++)
            #pragma unroll
            for (int ni = 0; ni < 4; ni++)
                acc[mi][ni] = __builtin_amdgcn_mfma_f32_16x16x32_f16(af[mi], bf[ni], acc[mi][ni], 0, 0, 0);

        if (it + 1 < nIt) {
            __syncthreads();            // all reads done before overwrite
            STAGE((size_t)(it + 1) * 32);
        }
    }
    #undef STAGE

    int rbase = blockIdx.x * 128 + wm * 64 + g4 * 4;
    int cbase = cb * 128 + wn * 64 + l15;
    #pragma unroll
    for (int mi = 0; mi < 4; mi++)
        #pragma unroll
        for (int r = 0; r < 4; r++) {
            float* crow = Csel + (size_t)(rbase + mi * 16 + r) * ldc + cbase;
            #pragma unroll
            for (int ni = 0; ni < 4; ni++) crow[ni * 16] = acc[mi][ni][r];
        }
}

// ---------------- fused RMSNorm + RoPE (in-place, fp32) ----------------
__global__ void rmsnorm_rope_k(float* __restrict__ X, const float* __restrict__ w,
                               const float* __restrict__ cosT, const float* __restrict__ sinT,
                               int heads, float outScale) {
    int gw = (int)((blockIdx.x * (size_t)blockDim.x + threadIdx.x) >> 6);
    int lane = threadIdx.x & 63;
    float* row = X + (size_t)gw * HD_;
    int t = (gw / heads) % T_;   // row index = (b*T + t)*heads + h
    float x0 = row[lane];
    float x1 = row[lane + 64];
    float ss = x0 * x0 + x1 * x1;
    #pragma unroll
    for (int off = 1; off < 64; off <<= 1) ss += __shfl_xor(ss, off);
    float inv = rsqrtf(ss * (1.0f / 128.0f) + 1e-6f);
    float n0 = x0 * inv * w[lane];
    float n1 = x1 * inv * w[lane + 64];
    float c = cosT[t * 64 + lane];
    float s = sinT[t * 64 + lane];
    row[lane]      = (n0 * c - n1 * s) * outScale;
    row[lane + 64] = (n1 * c + n0 * s) * outScale;
}

// ---------------- causal GQA flash attention (MFMA) ----------------
// Grid: (T/64, H, B). Block: 256 = 4 waves; wave w owns q-rows [qb*64+w*16, +16).
__global__ void __launch_bounds__(256) attn_mfma(const float* __restrict__ Q,
                                                 const float* __restrict__ Kt,
                                                 const float* __restrict__ Vt,
                                                 _Float16* __restrict__ ctx) {
    int qb = blockIdx.x, h = blockIdx.y, b = blockIdx.z;
    int g = h >> 2;
    int tid = threadIdx.x;
    int w = tid >> 6, lane = tid & 63;
    int l15 = lane & 15, g4 = lane >> 4;

    __shared__ _Float16 sK[32 * 136];
    __shared__ _Float16 sVT[128 * 40];
    __shared__ _Float16 sP[4 * 16 * 40];

    int qbase = qb * 64 + w * 16;
    int qg = qbase + l15;

    // Q fragments (B-operand: col = l15 = q row, k = g4*8 + step*32 + j)
    half8 qfrag[4];
    {
        const float* qrow = Q + ((size_t)((b * T_ + qbase + l15) * H_ + h)) * HD_ + g4 * 8;
        #pragma unroll
        for (int st = 0; st < 4; st++)
            #pragma unroll
            for (int j = 0; j < 8; j++) qfrag[st][j] = (_Float16)qrow[st * 32 + j];
    }

    f32x4 o[8];
    #pragma unroll
    for (int i = 0; i < 8; i++) o[i] = (f32x4){0.f, 0.f, 0.f, 0.f};
    float m = -INFINITY, lsum = 0.f;

    int row = tid >> 3, seg = tid & 7;      // staging: row = key 0..31, seg = 16-dim chunk
    int kend = qb * 64 + 64;
    int wkend = qbase + 16;                  // this wave's causal frontier

    for (int kt = 0; kt < kend; kt += 32) {
        __syncthreads();                     // previous tile's LDS reads done
        {
            size_t gbase = ((size_t)((b * T_ + kt + row) * G_ + g)) * HD_ + seg * 16;
            const float* kg_ = Kt + gbase;
            const float* vg_ = Vt + gbase;
            half8 h0, h1;
            #pragma unroll
            for (int j = 0; j < 8; j++) { h0[j] = (_Float16)kg_[j]; h1[j] = (_Float16)kg_[8 + j]; }
            *(half8*)&sK[row * 136 + seg * 16] = h0;
            *(half8*)&sK[row * 136 + seg * 16 + 8] = h1;
            // V transpose: sVT[d][k], granule-swizzled by (d>>4)&3 = seg&3
            #pragma unroll
            for (int j = 0; j < 16; j++) {
                int d = seg * 16 + j;
                int idx = d * 40 + (((row >> 3) ^ (seg & 3)) << 3) + (row & 7);
                sVT[idx] = (_Float16)vg_[j];
            }
        }
        __syncthreads();

        if (kt < wkend) {
            // S^T = K * Q^T : lane holds S[k = kt + 16*sub + 4*g4 + r][q = qg]
            f32x4 stc[2];
            stc[0] = (f32x4){0.f, 0.f, 0.f, 0.f};
            stc[1] = (f32x4){0.f, 0.f, 0.f, 0.f};
            #pragma unroll
            for (int st = 0; st < 4; st++) {
                half8 kf0 = *(const half8*)&sK[l15 * 136 + g4 * 8 + st * 32];
                half8 kf1 = *(const half8*)&sK[(l15 + 16) * 136 + g4 * 8 + st * 32];
                stc[0] = __builtin_amdgcn_mfma_f32_16x16x32_f16(kf0, qfrag[st], stc[0], 0, 0, 0);
                stc[1] = __builtin_amdgcn_mfma_f32_16x16x32_f16(kf1, qfrag[st], stc[1], 0, 0, 0);
            }
            // causal mask
            float sv[8];
            #pragma unroll
            for (int sub = 0; sub < 2; sub++)
                #pragma unroll
                for (int r = 0; r < 4; r++) {
                    int kgi = kt + 16 * sub + 4 * g4 + r;
                    sv[sub * 4 + r] = (kgi <= qg) ? stc[sub][r] : -INFINITY;
                }
            // online softmax over k for column q = l15 (+xor16/32 lane groups)
            float tmax = sv[0];
            #pragma unroll
            for (int i = 1; i < 8; i++) tmax = fmaxf(tmax, sv[i]);
            tmax = fmaxf(tmax, __shfl_xor(tmax, 16));
            tmax = fmaxf(tmax, __shfl_xor(tmax, 32));
            float nm = fmaxf(m, tmax);
            float alpha = __expf(m - nm);    // first tile: exp(-inf)=0
            float p[8], rsum = 0.f;
            #pragma unroll
            for (int i = 0; i < 8; i++) { p[i] = __expf(sv[i] - nm); rsum += p[i]; }
            rsum += __shfl_xor(rsum, 16);
            rsum += __shfl_xor(rsum, 32);
            lsum = lsum * alpha + rsum;
            m = nm;
            // rescale O (O's q index = 4*g4 + r; alpha lives at lane q = l15)
            #pragma unroll
            for (int r = 0; r < 4; r++) {
                float ar = __shfl(alpha, 4 * g4 + r);
                #pragma unroll
                for (int d = 0; d < 8; d++) o[d][r] *= ar;
            }
            // P -> LDS: sP[w][q = l15][k' = 16*sub + 4*g4 + r] as half2 pairs
            _Float16* pw = &sP[w * 640];
            #pragma unroll
            for (int sub = 0; sub < 2; sub++)
                #pragma unroll
                for (int rp = 0; rp < 4; rp += 2) {
                    half2_t hp;
                    hp[0] = (_Float16)p[sub * 4 + rp];
                    hp[1] = (_Float16)p[sub * 4 + rp + 1];
                    *(half2_t*)&pw[l15 * 40 + 16 * sub + 4 * g4 + rp] = hp;
                }
            asm volatile("s_waitcnt lgkmcnt(0)" ::: "memory");
            __builtin_amdgcn_sched_barrier(0);
            // PV: O[q][d] += P[16x32] * V^T ; A-frag: P[row=l15][k=8*g4+j]
            half8 pf = *(const half8*)&pw[l15 * 40 + g4 * 8];
            #pragma unroll
            for (int d = 0; d < 8; d++) {
                int vrow = l15 + 16 * d;
                half8 vf = *(const half8*)&sVT[vrow * 40 + ((g4 ^ (d & 3)) << 3)];
                o[d] = __builtin_amdgcn_mfma_f32_16x16x32_f16(pf, vf, o[d], 0, 0, 0);
            }
        }
    }

    // epilogue: O's q = 4*g4 + r; 1/lsum lives at lane q = l15
    float invl = 1.0f / lsum;
    #pragma unroll
    for (int r = 0; r < 4; r++) {
        float ir = __shfl(invl, 4 * g4 + r);
        _Float16* orow = ctx + (size_t)(b * T_ + qbase + 4 * g4 + r) * (H_ * HD_) + h * HD_ + l15;
        #pragma unroll
        for (int d = 0; d < 8; d++) orow[d * 16] = (_Float16)(o[d][r] * ir);
    }
}

// ---------------- launch ----------------
extern "C" void kernel_launch(void* const* d_in, const int* in_sizes, int n_in,
                              void* d_out, int out_size, void* d_ws, size_t ws_size,
                              hipStream_t stream) {
    const float* x   = (const float*)d_in[0];
    const float* Wq  = (const float*)d_in[1];
    const float* Wk  = (const float*)d_in[2];
    const float* Wv  = (const float*)d_in[3];
    const float* Wo  = (const float*)d_in[4];
    const float* qnw = (const float*)d_in[5];
    const float* knw = (const float*)d_in[6];
    float* out = (float*)d_out;

    char* ws = (char*)d_ws;
    size_t off = 0;
    auto alloc = [&](size_t bytes) {
        char* p = ws + off;
        off += (bytes + 255) & ~(size_t)255;
        return p;
    };
    _Float16* x_h  = (_Float16*)alloc((size_t)B_ * T_ * D_ * 2);
    _Float16* wq_h = (_Float16*)alloc((size_t)H_ * HD_ * D_ * 2);
    _Float16* wk_h = (_Float16*)alloc((size_t)G_ * HD_ * D_ * 2);
    _Float16* wv_h = (_Float16*)alloc((size_t)G_ * HD_ * D_ * 2);
    _Float16* wo_h = (_Float16*)alloc((size_t)D_ * H_ * HD_ * 2);
    float* q_f = (float*)alloc((size_t)B_ * T_ * H_ * HD_ * 4);
    float* k_f = (float*)alloc((size_t)B_ * T_ * G_ * HD_ * 4);
    float* v_f = (float*)alloc((size_t)B_ * T_ * G_ * HD_ * 4);
    _Float16* ctx_h = (_Float16*)alloc((size_t)B_ * T_ * H_ * HD_ * 2);
    float* cosT = (float*)alloc((size_t)T_ * 64 * 4);
    float* sinT = (float*)alloc((size_t)T_ * 64 * 4);

    // dtype conversions
    cvt_f16<<<2048, 256, 0, stream>>>(x,  x_h,  B_ * T_ * D_);
    cvt_f16<<<2048, 256, 0, stream>>>(Wq, wq_h, H_ * HD_ * D_);
    cvt_f16<<<1024, 256, 0, stream>>>(Wk, wk_h, G_ * HD_ * D_);
    cvt_f16<<<1024, 256, 0, stream>>>(Wv, wv_h, G_ * HD_ * D_);
    cvt_f16<<<2048, 256, 0, stream>>>(Wo, wo_h, D_ * H_ * HD_);
    rope_tables_k<<<(T_ * 64) / 256, 256, 0, stream>>>(cosT, sinT);

    // Q projection: M=4096, N=2048 (16 col-tiles)
    gemm_tile<<<dim3(32, 16), 256, 0, stream>>>(x_h, wq_h, q_f, 16, nullptr, nullptr, 0, D_);
    // fused K+V projection: two N=512 outputs (4+4 col-tiles)
    gemm_tile<<<dim3(32, 8), 256, 0, stream>>>(x_h, wk_h, k_f, 4, wv_h, v_f, 4, D_);

    // norm + rope; fold score scale (1/HD = 1/128) into Q
    rmsnorm_rope_k<<<(B_ * T_ * H_) / 4, 256, 0, stream>>>(q_f, qnw, cosT, sinT, H_, 1.0f / 128.0f);
    rmsnorm_rope_k<<<(B_ * T_ * G_) / 4, 256, 0, stream>>>(k_f, knw, cosT, sinT, G_, 1.0f);

    // causal GQA attention -> ctx (f16)
    attn_mfma<<<dim3(T_ / 64, H_, B_), 256, 0, stream>>>(q_f, k_f, v_f, ctx_h);

    // output projection -> d_out (fp32)
    gemm_tile<<<dim3(32, 16), 256, 0, stream>>>(ctx_h, wo_h, out, 16, nullptr, nullptr, 0, H_ * HD_);
}

// Round 4
// 322.931 us; speedup vs baseline: 6.6880x; 1.1730x over previous
//
#include <hip/hip_runtime.h>
#include <hip/hip_bf16.h>

// Problem constants (match reference)
#define B_ 2
#define T_ 2048
#define D_ 2048
#define H_ 16
#define G_ 4
#define HD_ 128
#define GS_ (H_/G_)

typedef _Float16 half8 __attribute__((ext_vector_type(8)));
typedef _Float16 half2_t __attribute__((ext_vector_type(2)));
typedef float f32x4 __attribute__((ext_vector_type(4)));

// ---------------- fp32 -> fp16 conversion ----------------
__global__ void cvt_f16(const float* __restrict__ in, _Float16* __restrict__ out, int n) {
    int i = blockIdx.x * blockDim.x + threadIdx.x;
    int stride = blockDim.x * gridDim.x;
    for (; i < n; i += stride) out[i] = (_Float16)in[i];
}

// ---------------- RoPE tables: cos/sin (T_, 64) ----------------
__global__ void rope_tables_k(float* __restrict__ cosT, float* __restrict__ sinT) {
    int i = blockIdx.x * blockDim.x + threadIdx.x; // T_*64 threads
    int t = i >> 6, l = i & 63;
    float inv_freq = powf(10000.0f, -((float)(2 * l)) / 128.0f);
    float a = (float)t * inv_freq;
    cosT[i] = cosf(a);
    sinT[i] = sinf(a);
}

// ---------------- Tiled TN GEMM (m97 structure) ----------------
__global__ void __launch_bounds__(256) gemm_tile(const _Float16* __restrict__ A,
                                                 const _Float16* __restrict__ B0,
                                                 float* __restrict__ C0, int n0t,
                                                 const _Float16* __restrict__ B1,
                                                 float* __restrict__ C1, int n1t,
                                                 int Kd) {
    __shared__ _Float16 sA[128 * 32];
    __shared__ _Float16 sB[128 * 32];

    int tid = threadIdx.x;
    int w = tid >> 6, lane = tid & 63;
    int l15 = lane & 15, g4 = lane >> 4;
    int wm = w >> 1, wn = w & 1;

    const _Float16* Bsel;
    float* Csel;
    int ldc, cb;
    if ((int)blockIdx.y < n0t) { Bsel = B0; Csel = C0; ldc = n0t * 128; cb = blockIdx.y; }
    else                       { Bsel = B1; Csel = C1; ldc = n1t * 128; cb = blockIdx.y - n0t; }

    const _Float16* Ab = A + (size_t)(blockIdx.x * 128) * Kd;
    const _Float16* Bb = Bsel + (size_t)(cb * 128) * Kd;

    int s0 = w * 128 + lane;
    int s1 = s0 + 64;
    int r0 = s0 >> 2, c0 = s0 & 3;
    int r1 = s1 >> 2, c1 = s1 & 3;
    size_t ga0 = (size_t)r0 * Kd + c0 * 8;
    size_t ga1 = (size_t)r1 * Kd + c1 * 8;
    _Float16* lds_a0 = sA + (size_t)(w * 2) * 512;
    _Float16* lds_a1 = sA + (size_t)(w * 2 + 1) * 512;
    _Float16* lds_b0 = sB + (size_t)(w * 2) * 512;
    _Float16* lds_b1 = sB + (size_t)(w * 2 + 1) * 512;

    #define STAGE(K0)                                                                     \
        do {                                                                              \
            __builtin_amdgcn_global_load_lds(                                             \
                (const __attribute__((address_space(1))) unsigned int*)(Ab + ga0 + (K0)), \
                (__attribute__((address_space(3))) unsigned int*)lds_a0, 16, 0, 0);       \
            __builtin_amdgcn_global_load_lds(                                             \
                (const __attribute__((address_space(1))) unsigned int*)(Ab + ga1 + (K0)), \
                (__attribute__((address_space(3))) unsigned int*)lds_a1, 16, 0, 0);       \
            __builtin_amdgcn_global_load_lds(                                             \
                (const __attribute__((address_space(1))) unsigned int*)(Bb + ga0 + (K0)), \
                (__attribute__((address_space(3))) unsigned int*)lds_b0, 16, 0, 0);       \
            __builtin_amdgcn_global_load_lds(                                             \
                (const __attribute__((address_space(1))) unsigned int*)(Bb + ga1 + (K0)), \
                (__attribute__((address_space(3))) unsigned int*)lds_b1, 16, 0, 0);       \
        } while (0)

    f32x4 acc[4][4];
    #pragma unroll
    for (int i = 0; i < 4; i++)
        #pragma unroll
        for (int j = 0; j < 4; j++) acc[i][j] = (f32x4){0.f, 0.f, 0.f, 0.f};

    STAGE(0);

    int nIt = Kd >> 5;
    for (int it = 0; it < nIt; ++it) {
        __syncthreads();

        half8 af[4], bf[4];
        #pragma unroll
        for (int mi = 0; mi < 4; mi++)
            af[mi] = *(const half8*)&sA[(wm * 64 + mi * 16 + l15) * 32 + g4 * 8];
        #pragma unroll
        for (int ni = 0; ni < 4; ni++)
            bf[ni] = *(const half8*)&sB[(wn * 64 + ni * 16 + l15) * 32 + g4 * 8];

        #pragma unroll
        for (int mi = 0; mi < 4; mi++)
            #pragma unroll
            for (int ni = 0; ni < 4; ni++)
                acc[mi][ni] = __builtin_amdgcn_mfma_f32_16x16x32_f16(af[mi], bf[ni], acc[mi][ni], 0, 0, 0);

        if (it + 1 < nIt) {
            __syncthreads();
            STAGE((size_t)(it + 1) * 32);
        }
    }
    #undef STAGE

    int rbase = blockIdx.x * 128 + wm * 64 + g4 * 4;
    int cbase = cb * 128 + wn * 64 + l15;
    #pragma unroll
    for (int mi = 0; mi < 4; mi++)
        #pragma unroll
        for (int r = 0; r < 4; r++) {
            float* crow = Csel + (size_t)(rbase + mi * 16 + r) * ldc + cbase;
            #pragma unroll
            for (int ni = 0; ni < 4; ni++) crow[ni * 16] = acc[mi][ni][r];
        }
}

// ---------------- fused RMSNorm + RoPE ----------------
// One wave per 128-elem row. outH != nullptr -> write f16 there; else in-place f32.
__global__ void rmsnorm_rope_k(float* __restrict__ X, const float* __restrict__ w,
                               const float* __restrict__ cosT, const float* __restrict__ sinT,
                               int heads, float outScale, _Float16* __restrict__ outH) {
    int gw = (int)((blockIdx.x * (size_t)blockDim.x + threadIdx.x) >> 6);
    int lane = threadIdx.x & 63;
    float* row = X + (size_t)gw * HD_;
    int t = (gw / heads) % T_;   // row index = (b*T + t)*heads + h
    float x0 = row[lane];
    float x1 = row[lane + 64];
    float ss = x0 * x0 + x1 * x1;
    #pragma unroll
    for (int off = 1; off < 64; off <<= 1) ss += __shfl_xor(ss, off);
    float inv = rsqrtf(ss * (1.0f / 128.0f) + 1e-6f);
    float n0 = x0 * inv * w[lane];
    float n1 = x1 * inv * w[lane + 64];
    float c = cosT[t * 64 + lane];
    float s = sinT[t * 64 + lane];
    float r0 = (n0 * c - n1 * s) * outScale;
    float r1 = (n1 * c + n0 * s) * outScale;
    if (outH) {
        outH[(size_t)gw * HD_ + lane]      = (_Float16)r0;
        outH[(size_t)gw * HD_ + lane + 64] = (_Float16)r1;
    } else {
        row[lane]      = r0;
        row[lane + 64] = r1;
    }
}

// ---------------- pack K: f32 k_f -> f16 swizzled tile image ----------------
// kimg tile (b,g,tile): [key 0..63][128 f16], content[key][pos] = K[key][pos ^ ((key&7)<<3)]
// i.e. granule g0 holds src d-granule (g0 ^ (key&7)).
__global__ void pack_k(const float* __restrict__ kf, _Float16* __restrict__ kimg) {
    int gid = blockIdx.x * blockDim.x + threadIdx.x;   // 262144 granules
    int g0   = gid & 15;
    int key  = (gid >> 4) & 63;
    int tile = (gid >> 10) & 31;
    int g    = (gid >> 15) & 3;
    int b    = gid >> 17;
    const float* src = kf + ((size_t)(b * T_ + tile * 64 + key)) * (G_ * HD_) + g * HD_ + ((g0 ^ (key & 7)) * 8);
    half8 hv;
    #pragma unroll
    for (int j = 0; j < 8; j++) hv[j] = (_Float16)src[j];
    *(half8*)(kimg + (size_t)gid * 8) = hv;
}

// ---------------- pack V: f32 v_f -> f16 transposed swizzled tile image ----------------
// vimg tile (b,g,tile): [d 0..127][64 f16], content[d][pos] = V[pos ^ ((d&7)<<3)][d].
// LDS transpose with matching XOR so phase-2 reads are contiguous half8.
__global__ void __launch_bounds__(256) pack_v(const float* __restrict__ vf, _Float16* __restrict__ vimg) {
    __shared__ _Float16 sT[128 * 80];
    int bid = blockIdx.x;             // (b,g,tile)
    int tile = bid & 31, g = (bid >> 5) & 3, b = bid >> 7;
    int tid = threadIdx.x;
    const float* base = vf + ((size_t)(b * T_ + tile * 64)) * (G_ * HD_) + g * HD_;
    #pragma unroll
    for (int it = 0; it < 32; it++) {
        int i = tid + 256 * it;       // i = key*128 + d
        int key = i >> 7, d = i & 127;
        float v = base[(size_t)key * (G_ * HD_) + d];
        sT[d * 80 + (key ^ ((d & 7) << 3))] = (_Float16)v;
    }
    __syncthreads();
    _Float16* out = vimg + (size_t)bid * 8192;
    #pragma unroll
    for (int it = 0; it < 4; it++) {
        int og = tid + 256 * it;      // og = d*8 + gk
        int d = og >> 3, gk = og & 7;
        half8 hv = *(const half8*)&sT[d * 80 + gk * 8];
        *(half8*)(out + (size_t)og * 8) = hv;
    }
}

// ---------------- causal GQA flash attention v2 (MFMA, packed images) ----------------
// Block: 4 waves x 32 q-rows = 128 q-rows, one head. KV tiles of 64 keys.
// sK/sV staged linearly from pre-swizzled images via global_load_lds(16B).
// All LDS reads/writes use byte ^ ((row&7)<<4) swizzle (m214-verified).
__global__ void __launch_bounds__(256) attn_mfma2(const _Float16* __restrict__ qh,
                                                  const _Float16* __restrict__ kimg,
                                                  const _Float16* __restrict__ vimg,
                                                  _Float16* __restrict__ ctx) {
    // balanced grid decode: pair (qb, 15-qb) across the two halves of the grid
    int id = blockIdx.x;
    int hlf = id >> 8, rr0 = id & 255;
    int qb = hlf ? (15 - (rr0 & 15)) : (rr0 & 15);
    int hb = (rr0 >> 4) | (hlf << 4);
    int h = hb & 15, b = hb >> 4;
    int g = h >> 2;

    int tid = threadIdx.x;
    int w = tid >> 6, lane = tid & 63;
    int l15 = lane & 15, g4 = lane >> 4;
    int l7x = (l15 & 7) << 4;          // byte-XOR swizzle term

    __shared__ _Float16 sK[64 * 128];  // 16 KB (swizzled image of 64 keys x 128 d)
    __shared__ _Float16 sV[128 * 64];  // 16 KB (swizzled image of V^T: 128 d x 64 keys)
    __shared__ _Float16 sP[4 * 32 * 64]; // 16 KB, per-wave 4 KB

    const char* sKb = (const char*)sK;
    const char* sVb = (const char*)sV;
    char* sPb = (char*)sP + w * 4096;

    int qbase = qb * 128 + w * 32;

    // Q fragments (B-operand): qfrag[qt][st] = Q[qbase+qt*16+l15][st*32 + g4*8 + j]
    half8 qfrag[2][4];
    #pragma unroll
    for (int qt = 0; qt < 2; qt++) {
        const _Float16* qrow = qh + ((size_t)(b * T_ + qbase + qt * 16 + l15)) * (H_ * HD_) + h * HD_ + g4 * 8;
        #pragma unroll
        for (int st = 0; st < 4; st++)
            qfrag[qt][st] = *(const half8*)(qrow + st * 32);
    }

    f32x4 o[2][8];
    #pragma unroll
    for (int qt = 0; qt < 2; qt++)
        #pragma unroll
        for (int dt = 0; dt < 8; dt++) o[qt][dt] = (f32x4){0.f, 0.f, 0.f, 0.f};
    float m[2] = {-INFINITY, -INFINITY}, lsum[2] = {0.f, 0.f};

    const _Float16* kbase = kimg + ((size_t)((b * 4 + g) * 32)) * 8192;
    const _Float16* vbase = vimg + ((size_t)((b * 4 + g) * 32)) * 8192;
    int lo8 = lane * 8;                // lane 16B offset in f16

    #define STAGE_T(KT)                                                                          \
        do {                                                                                     \
            size_t tb = (size_t)(KT) * 8192 + w * 2048;                                          \
            _Float16* dK = sK + w * 2048;                                                        \
            _Float16* dV = sV + w * 2048;                                                        \
            _Pragma("unroll")                                                                    \
            for (int i_ = 0; i_ < 4; i_++) {                                                     \
                __builtin_amdgcn_global_load_lds(                                                \
                    (const __attribute__((address_space(1))) unsigned int*)(kbase + tb + i_ * 512 + lo8), \
                    (__attribute__((address_space(3))) unsigned int*)(dK + i_ * 512), 16, 0, 0); \
                __builtin_amdgcn_global_load_lds(                                                \
                    (const __attribute__((address_space(1))) unsigned int*)(vbase + tb + i_ * 512 + lo8), \
                    (__attribute__((address_space(3))) unsigned int*)(dV + i_ * 512), 16, 0, 0); \
            }                                                                                    \
        } while (0)

    int nt = 2 * qb + 2;
    int ktmax_w = (qbase + 31) >> 6;

    STAGE_T(0);

    for (int kt = 0; kt < nt; kt++) {
        __syncthreads();   // staging complete (compiler drains vmcnt)

        if (kt <= ktmax_w) {
            // ---- QK^T (swapped): stc[kt4][qt], D[key-sub, q-sub] ----
            f32x4 stc[4][2];
            #pragma unroll
            for (int kt4 = 0; kt4 < 4; kt4++)
                #pragma unroll
                for (int qt = 0; qt < 2; qt++) stc[kt4][qt] = (f32x4){0.f, 0.f, 0.f, 0.f};
            #pragma unroll
            for (int ks = 0; ks < 4; ks++) {
                #pragma unroll
                for (int kt4 = 0; kt4 < 4; kt4++) {
                    int key = kt4 * 16 + l15;
                    half8 kf = *(const half8*)(sKb + key * 256 + ((ks * 64 + g4 * 16) ^ l7x));
                    stc[kt4][0] = __builtin_amdgcn_mfma_f32_16x16x32_f16(kf, qfrag[0][ks], stc[kt4][0], 0, 0, 0);
                    stc[kt4][1] = __builtin_amdgcn_mfma_f32_16x16x32_f16(kf, qfrag[1][ks], stc[kt4][1], 0, 0, 0);
                }
            }

            // ---- softmax per q-subtile ----
            #pragma unroll
            for (int qt = 0; qt < 2; qt++) {
                int q = qbase + qt * 16 + l15;
                float sv[16];
                #pragma unroll
                for (int kt4 = 0; kt4 < 4; kt4++)
                    #pragma unroll
                    for (int r = 0; r < 4; r++) {
                        int keyg = kt * 64 + kt4 * 16 + 4 * g4 + r;
                        sv[kt4 * 4 + r] = (keyg <= q) ? stc[kt4][qt][r] : -INFINITY;
                    }
                float tmax = sv[0];
                #pragma unroll
                for (int i = 1; i < 16; i++) tmax = fmaxf(tmax, sv[i]);
                tmax = fmaxf(tmax, __shfl_xor(tmax, 16));
                tmax = fmaxf(tmax, __shfl_xor(tmax, 32));
                float nm = fmaxf(m[qt], tmax);
                float alpha = __expf(m[qt] - nm);   // exp(-inf)=0 on first tile
                float p[16], rsum = 0.f;
                #pragma unroll
                for (int i = 0; i < 16; i++) { p[i] = __expf(sv[i] - nm); rsum += p[i]; }
                rsum += __shfl_xor(rsum, 16);
                rsum += __shfl_xor(rsum, 32);
                lsum[qt] = lsum[qt] * alpha + rsum;
                m[qt] = nm;
                #pragma unroll
                for (int r = 0; r < 4; r++) {
                    float ar = __shfl(alpha, 4 * g4 + r);
                    #pragma unroll
                    for (int dt = 0; dt < 8; dt++) o[qt][dt][r] *= ar;
                }
                // P -> sP (swizzled): row q' = qt*16+l15, key byte = key*2
                #pragma unroll
                for (int kt4 = 0; kt4 < 4; kt4++)
                    #pragma unroll
                    for (int rp = 0; rp < 4; rp += 2) {
                        half2_t hp;
                        hp[0] = (_Float16)p[kt4 * 4 + rp];
                        hp[1] = (_Float16)p[kt4 * 4 + rp + 1];
                        *(half2_t*)(sPb + (qt * 16 + l15) * 128 +
                                    ((kt4 * 32 + g4 * 8 + rp * 2) ^ l7x)) = hp;
                    }
            }
            asm volatile("s_waitcnt lgkmcnt(0)" ::: "memory");
            __builtin_amdgcn_sched_barrier(0);

            // ---- PV: O[q][d] += P * V ----
            #pragma unroll
            for (int ks = 0; ks < 2; ks++) {
                half8 pf0 = *(const half8*)(sPb + l15 * 128 + ((ks * 64 + g4 * 16) ^ l7x));
                half8 pf1 = *(const half8*)(sPb + (16 + l15) * 128 + ((ks * 64 + g4 * 16) ^ l7x));
                #pragma unroll
                for (int dt = 0; dt < 8; dt++) {
                    int d = dt * 16 + l15;
                    half8 vfr = *(const half8*)(sVb + d * 128 + ((ks * 64 + g4 * 16) ^ l7x));
                    o[0][dt] = __builtin_amdgcn_mfma_f32_16x16x32_f16(pf0, vfr, o[0][dt], 0, 0, 0);
                    o[1][dt] = __builtin_amdgcn_mfma_f32_16x16x32_f16(pf1, vfr, o[1][dt], 0, 0, 0);
                }
            }
        }

        if (kt + 1 < nt) {
            __syncthreads();
            STAGE_T(kt + 1);
        }
    }
    #undef STAGE_T

    // epilogue: O q-sub = 4*g4 + r (per qt); 1/lsum lives at lane l15 = q-sub
    #pragma unroll
    for (int qt = 0; qt < 2; qt++) {
        float invl = 1.0f / lsum[qt];
        #pragma unroll
        for (int r = 0; r < 4; r++) {
            float ir = __shfl(invl, 4 * g4 + r);
            _Float16* orow = ctx + (size_t)(b * T_ + qbase + qt * 16 + 4 * g4 + r) * (H_ * HD_) + h * HD_ + l15;
            #pragma unroll
            for (int dt = 0; dt < 8; dt++) orow[dt * 16] = (_Float16)(o[qt][dt][r] * ir);
        }
    }
}

// ---------------- launch ----------------
extern "C" void kernel_launch(void* const* d_in, const int* in_sizes, int n_in,
                              void* d_out, int out_size, void* d_ws, size_t ws_size,
                              hipStream_t stream) {
    const float* x   = (const float*)d_in[0];
    const float* Wq  = (const float*)d_in[1];
    const float* Wk  = (const float*)d_in[2];
    const float* Wv  = (const float*)d_in[3];
    const float* Wo  = (const float*)d_in[4];
    const float* qnw = (const float*)d_in[5];
    const float* knw = (const float*)d_in[6];
    float* out = (float*)d_out;

    char* ws = (char*)d_ws;
    size_t off = 0;
    auto alloc = [&](size_t bytes) {
        char* p = ws + off;
        off += (bytes + 255) & ~(size_t)255;
        return p;
    };
    _Float16* x_h  = (_Float16*)alloc((size_t)B_ * T_ * D_ * 2);        // also reused as q_h
    _Float16* wq_h = (_Float16*)alloc((size_t)H_ * HD_ * D_ * 2);       // also reused as kimg+vimg
    _Float16* wk_h = (_Float16*)alloc((size_t)G_ * HD_ * D_ * 2);
    _Float16* wv_h = (_Float16*)alloc((size_t)G_ * HD_ * D_ * 2);
    _Float16* wo_h = (_Float16*)alloc((size_t)D_ * H_ * HD_ * 2);
    float* q_f = (float*)alloc((size_t)B_ * T_ * H_ * HD_ * 4);
    float* k_f = (float*)alloc((size_t)B_ * T_ * G_ * HD_ * 4);
    float* v_f = (float*)alloc((size_t)B_ * T_ * G_ * HD_ * 4);
    _Float16* ctx_h = (_Float16*)alloc((size_t)B_ * T_ * H_ * HD_ * 2);
    float* cosT = (float*)alloc((size_t)T_ * 64 * 4);
    float* sinT = (float*)alloc((size_t)T_ * 64 * 4);

    // aliases (lifetimes disjoint with originals):
    _Float16* q_h  = x_h;                       // x_h dead after GEMMs; q_h same size (16.8 MB)
    _Float16* kimg = wq_h;                      // wq_h dead after Q GEMM; kimg 4 MB
    _Float16* vimg = wq_h + (size_t)2 * 4 * 32 * 8192;  // next 4 MB of wq_h (8 MB total)

    // dtype conversions
    cvt_f16<<<2048, 256, 0, stream>>>(x,  x_h,  B_ * T_ * D_);
    cvt_f16<<<2048, 256, 0, stream>>>(Wq, wq_h, H_ * HD_ * D_);
    cvt_f16<<<1024, 256, 0, stream>>>(Wk, wk_h, G_ * HD_ * D_);
    cvt_f16<<<1024, 256, 0, stream>>>(Wv, wv_h, G_ * HD_ * D_);
    cvt_f16<<<2048, 256, 0, stream>>>(Wo, wo_h, D_ * H_ * HD_);
    rope_tables_k<<<(T_ * 64) / 256, 256, 0, stream>>>(cosT, sinT);

    // projections
    gemm_tile<<<dim3(32, 16), 256, 0, stream>>>(x_h, wq_h, q_f, 16, nullptr, nullptr, 0, D_);
    gemm_tile<<<dim3(32, 8), 256, 0, stream>>>(x_h, wk_h, k_f, 4, wv_h, v_f, 4, D_);

    // norm + rope; Q -> f16 (x_h buffer), score scale 1/128 folded into Q; K in-place f32
    rmsnorm_rope_k<<<(B_ * T_ * H_) / 4, 256, 0, stream>>>(q_f, qnw, cosT, sinT, H_, 1.0f / 128.0f, q_h);
    rmsnorm_rope_k<<<(B_ * T_ * G_) / 4, 256, 0, stream>>>(k_f, knw, cosT, sinT, G_, 1.0f, nullptr);

    // pack K/V into swizzled f16 tile images (reusing wq_h)
    pack_k<<<1024, 256, 0, stream>>>(k_f, kimg);
    pack_v<<<256, 256, 0, stream>>>(v_f, vimg);

    // causal GQA attention -> ctx (f16)
    attn_mfma2<<<512, 256, 0, stream>>>(q_h, kimg, vimg, ctx_h);

    // output projection -> d_out (fp32)
    gemm_tile<<<dim3(32, 16), 256, 0, stream>>>(ctx_h, wo_h, out, 16, nullptr, nullptr, 0, H_ * HD_);
}

// Round 5
// 302.437 us; speedup vs baseline: 7.1412x; 1.0678x over previous
//
#include <hip/hip_runtime.h>
#include <hip/hip_bf16.h>

// Problem constants (match reference)
#define B_ 2
#define T_ 2048
#define D_ 2048
#define H_ 16
#define G_ 4
#define HD_ 128
#define GS_ (H_/G_)

typedef _Float16 half8 __attribute__((ext_vector_type(8)));
typedef _Float16 half2_t __attribute__((ext_vector_type(2)));
typedef float f32x4 __attribute__((ext_vector_type(4)));

// ---------------- fp32 -> fp16 conversion ----------------
__global__ void cvt_f16(const float* __restrict__ in, _Float16* __restrict__ out, int n) {
    int i = blockIdx.x * blockDim.x + threadIdx.x;
    int stride = blockDim.x * gridDim.x;
    for (; i < n; i += stride) out[i] = (_Float16)in[i];
}

// ---------------- RoPE tables: cos/sin (T_, 64) ----------------
__global__ void rope_tables_k(float* __restrict__ cosT, float* __restrict__ sinT) {
    int i = blockIdx.x * blockDim.x + threadIdx.x; // T_*64 threads
    int t = i >> 6, l = i & 63;
    float inv_freq = powf(10000.0f, -((float)(2 * l)) / 128.0f);
    float a = (float)t * inv_freq;
    cosT[i] = cosf(a);
    sinT[i] = sinf(a);
}

// ---------------- Tiled TN GEMM (m97 structure, up to 3 fused outputs) ----------------
// C[M,N] = A[M,K] * B[N,K]^T, f16 in / f32 out. 128x128 tile, BK=32, 4 waves.
__global__ void __launch_bounds__(256) gemm_tile(const _Float16* __restrict__ A,
                                                 const _Float16* __restrict__ B0,
                                                 float* __restrict__ C0, int n0t,
                                                 const _Float16* __restrict__ B1,
                                                 float* __restrict__ C1, int n1t,
                                                 const _Float16* __restrict__ B2,
                                                 float* __restrict__ C2, int n2t,
                                                 int Kd) {
    __shared__ _Float16 sA[128 * 32];
    __shared__ _Float16 sB[128 * 32];

    int tid = threadIdx.x;
    int w = tid >> 6, lane = tid & 63;
    int l15 = lane & 15, g4 = lane >> 4;
    int wm = w >> 1, wn = w & 1;

    int y = blockIdx.y;
    const _Float16* Bsel;
    float* Csel;
    int ldc, cb;
    if (y < n0t)            { Bsel = B0; Csel = C0; ldc = n0t * 128; cb = y; }
    else if (y < n0t + n1t) { Bsel = B1; Csel = C1; ldc = n1t * 128; cb = y - n0t; }
    else                    { Bsel = B2; Csel = C2; ldc = n2t * 128; cb = y - n0t - n1t; }

    const _Float16* Ab = A + (size_t)(blockIdx.x * 128) * Kd;
    const _Float16* Bb = Bsel + (size_t)(cb * 128) * Kd;

    int s0 = w * 128 + lane;
    int s1 = s0 + 64;
    int r0 = s0 >> 2, c0 = s0 & 3;
    int r1 = s1 >> 2, c1 = s1 & 3;
    size_t ga0 = (size_t)r0 * Kd + c0 * 8;
    size_t ga1 = (size_t)r1 * Kd + c1 * 8;
    _Float16* lds_a0 = sA + (size_t)(w * 2) * 512;
    _Float16* lds_a1 = sA + (size_t)(w * 2 + 1) * 512;
    _Float16* lds_b0 = sB + (size_t)(w * 2) * 512;
    _Float16* lds_b1 = sB + (size_t)(w * 2 + 1) * 512;

    #define STAGE(K0)                                                                     \
        do {                                                                              \
            __builtin_amdgcn_global_load_lds(                                             \
                (const __attribute__((address_space(1))) unsigned int*)(Ab + ga0 + (K0)), \
                (__attribute__((address_space(3))) unsigned int*)lds_a0, 16, 0, 0);       \
            __builtin_amdgcn_global_load_lds(                                             \
                (const __attribute__((address_space(1))) unsigned int*)(Ab + ga1 + (K0)), \
                (__attribute__((address_space(3))) unsigned int*)lds_a1, 16, 0, 0);       \
            __builtin_amdgcn_global_load_lds(                                             \
                (const __attribute__((address_space(1))) unsigned int*)(Bb + ga0 + (K0)), \
                (__attribute__((address_space(3))) unsigned int*)lds_b0, 16, 0, 0);       \
            __builtin_amdgcn_global_load_lds(                                             \
                (const __attribute__((address_space(1))) unsigned int*)(Bb + ga1 + (K0)), \
                (__attribute__((address_space(3))) unsigned int*)lds_b1, 16, 0, 0);       \
        } while (0)

    f32x4 acc[4][4];
    #pragma unroll
    for (int i = 0; i < 4; i++)
        #pragma unroll
        for (int j = 0; j < 4; j++) acc[i][j] = (f32x4){0.f, 0.f, 0.f, 0.f};

    STAGE(0);

    int nIt = Kd >> 5;
    for (int it = 0; it < nIt; ++it) {
        __syncthreads();

        half8 af[4], bf[4];
        #pragma unroll
        for (int mi = 0; mi < 4; mi++)
            af[mi] = *(const half8*)&sA[(wm * 64 + mi * 16 + l15) * 32 + g4 * 8];
        #pragma unroll
        for (int ni = 0; ni < 4; ni++)
            bf[ni] = *(const half8*)&sB[(wn * 64 + ni * 16 + l15) * 32 + g4 * 8];

        #pragma unroll
        for (int mi = 0; mi < 4; mi++)
            #pragma unroll
            for (int ni = 0; ni < 4; ni++)
                acc[mi][ni] = __builtin_amdgcn_mfma_f32_16x16x32_f16(af[mi], bf[ni], acc[mi][ni], 0, 0, 0);

        if (it + 1 < nIt) {
            __syncthreads();
            STAGE((size_t)(it + 1) * 32);
        }
    }
    #undef STAGE

    int rbase = blockIdx.x * 128 + wm * 64 + g4 * 4;
    int cbase = cb * 128 + wn * 64 + l15;
    #pragma unroll
    for (int mi = 0; mi < 4; mi++)
        #pragma unroll
        for (int r = 0; r < 4; r++) {
            float* crow = Csel + (size_t)(rbase + mi * 16 + r) * ldc + cbase;
            #pragma unroll
            for (int ni = 0; ni < 4; ni++) crow[ni * 16] = acc[mi][ni][r];
        }
}

// ---------------- fused RMSNorm + RoPE ----------------
__global__ void rmsnorm_rope_k(float* __restrict__ X, const float* __restrict__ w,
                               const float* __restrict__ cosT, const float* __restrict__ sinT,
                               int heads, float outScale, _Float16* __restrict__ outH) {
    int gw = (int)((blockIdx.x * (size_t)blockDim.x + threadIdx.x) >> 6);
    int lane = threadIdx.x & 63;
    float* row = X + (size_t)gw * HD_;
    int t = (gw / heads) % T_;   // row index = (b*T + t)*heads + h
    float x0 = row[lane];
    float x1 = row[lane + 64];
    float ss = x0 * x0 + x1 * x1;
    #pragma unroll
    for (int off = 1; off < 64; off <<= 1) ss += __shfl_xor(ss, off);
    float inv = rsqrtf(ss * (1.0f / 128.0f) + 1e-6f);
    float n0 = x0 * inv * w[lane];
    float n1 = x1 * inv * w[lane + 64];
    float c = cosT[t * 64 + lane];
    float s = sinT[t * 64 + lane];
    float r0 = (n0 * c - n1 * s) * outScale;
    float r1 = (n1 * c + n0 * s) * outScale;
    if (outH) {
        outH[(size_t)gw * HD_ + lane]      = (_Float16)r0;
        outH[(size_t)gw * HD_ + lane + 64] = (_Float16)r1;
    } else {
        row[lane]      = r0;
        row[lane + 64] = r1;
    }
}

// ---------------- pack K: f32 k_f -> f16 swizzled tile image ----------------
__global__ void pack_k(const float* __restrict__ kf, _Float16* __restrict__ kimg) {
    int gid = blockIdx.x * blockDim.x + threadIdx.x;   // 262144 granules
    int g0   = gid & 15;
    int key  = (gid >> 4) & 63;
    int tile = (gid >> 10) & 31;
    int g    = (gid >> 15) & 3;
    int b    = gid >> 17;
    const float* src = kf + ((size_t)(b * T_ + tile * 64 + key)) * (G_ * HD_) + g * HD_ + ((g0 ^ (key & 7)) * 8);
    half8 hv;
    #pragma unroll
    for (int j = 0; j < 8; j++) hv[j] = (_Float16)src[j];
    *(half8*)(kimg + (size_t)gid * 8) = hv;
}

// ---------------- pack V: f32 v_f -> f16 transposed swizzled tile image ----------------
__global__ void __launch_bounds__(256) pack_v(const float* __restrict__ vf, _Float16* __restrict__ vimg) {
    __shared__ _Float16 sT[128 * 80];
    int bid = blockIdx.x;             // (b,g,tile)
    int tile = bid & 31, g = (bid >> 5) & 3, b = bid >> 7;
    int tid = threadIdx.x;
    const float* base = vf + ((size_t)(b * T_ + tile * 64)) * (G_ * HD_) + g * HD_;
    #pragma unroll
    for (int it = 0; it < 32; it++) {
        int i = tid + 256 * it;       // i = key*128 + d
        int key = i >> 7, d = i & 127;
        float v = base[(size_t)key * (G_ * HD_) + d];
        sT[d * 80 + (key ^ ((d & 7) << 3))] = (_Float16)v;
    }
    __syncthreads();
    _Float16* out = vimg + (size_t)bid * 8192;
    #pragma unroll
    for (int it = 0; it < 4; it++) {
        int og = tid + 256 * it;      // og = d*8 + gk
        int d = og >> 3, gk = og & 7;
        half8 hv = *(const half8*)&sT[d * 80 + gk * 8];
        *(half8*)(out + (size_t)og * 8) = hv;
    }
}

// ---------------- causal GQA flash attention v3 (MFMA, 2-phase pipelined) ----------------
// Block: 4 waves x 32 q-rows = 128 q-rows, one head. KV tiles of 64 keys.
// Double-buffered sK/sV; STAGE of tile t+1 issued right after the top barrier,
// compute of tile t runs under the loads (T3/T14). One barrier per tile.
__global__ void __launch_bounds__(256) attn_mfma3(const _Float16* __restrict__ qh,
                                                  const _Float16* __restrict__ kimg,
                                                  const _Float16* __restrict__ vimg,
                                                  _Float16* __restrict__ ctx) {
    // balanced grid decode: block i and i+256 (same CU in the 2-deep dispatch) get qb and 15-qb
    int id = blockIdx.x;
    int hlf = id >> 8, rr0 = id & 255;
    int qb = hlf ? (15 - (rr0 & 15)) : (rr0 & 15);
    int hb = (rr0 >> 4) | (hlf << 4);
    int h = hb & 15, b = hb >> 4;
    int g = h >> 2;

    int tid = threadIdx.x;
    int w = tid >> 6, lane = tid & 63;
    int l15 = lane & 15, g4 = lane >> 4;
    int l7x = (l15 & 7) << 4;          // byte-XOR swizzle term

    __shared__ _Float16 sK[2][64 * 128];   // 2 x 16 KB
    __shared__ _Float16 sV[2][64 * 128];   // 2 x 16 KB
    __shared__ _Float16 sP[4 * 32 * 64];   // 16 KB, per-wave 4 KB

    char* sPb = (char*)sP + w * 4096;

    int qbase = qb * 128 + w * 32;

    // Q fragments (B-operand): qfrag[qt][st] = Q[qbase+qt*16+l15][st*32 + g4*8 + j]
    half8 qfrag[2][4];
    #pragma unroll
    for (int qt = 0; qt < 2; qt++) {
        const _Float16* qrow = qh + ((size_t)(b * T_ + qbase + qt * 16 + l15)) * (H_ * HD_) + h * HD_ + g4 * 8;
        #pragma unroll
        for (int st = 0; st < 4; st++)
            qfrag[qt][st] = *(const half8*)(qrow + st * 32);
    }

    f32x4 o[2][8];
    #pragma unroll
    for (int qt = 0; qt < 2; qt++)
        #pragma unroll
        for (int dt = 0; dt < 8; dt++) o[qt][dt] = (f32x4){0.f, 0.f, 0.f, 0.f};
    float m[2] = {-INFINITY, -INFINITY}, lsum[2] = {0.f, 0.f};

    const _Float16* kbase = kimg + ((size_t)((b * 4 + g) * 32)) * 8192;
    const _Float16* vbase = vimg + ((size_t)((b * 4 + g) * 32)) * 8192;
    int lo8 = lane * 8;                // lane 16B offset in f16

    #define STAGE_T(BUF, KT)                                                                     \
        do {                                                                                     \
            size_t tb = (size_t)(KT) * 8192 + w * 2048;                                          \
            _Float16* dK = &sK[BUF][0] + w * 2048;                                               \
            _Float16* dV = &sV[BUF][0] + w * 2048;                                               \
            _Pragma("unroll")                                                                    \
            for (int i_ = 0; i_ < 4; i_++) {                                                     \
                __builtin_amdgcn_global_load_lds(                                                \
                    (const __attribute__((address_space(1))) unsigned int*)(kbase + tb + i_ * 512 + lo8), \
                    (__attribute__((address_space(3))) unsigned int*)(dK + i_ * 512), 16, 0, 0); \
                __builtin_amdgcn_global_load_lds(                                                \
                    (const __attribute__((address_space(1))) unsigned int*)(vbase + tb + i_ * 512 + lo8), \
                    (__attribute__((address_space(3))) unsigned int*)(dV + i_ * 512), 16, 0, 0); \
            }                                                                                    \
        } while (0)

    int nt = 2 * qb + 2;
    int ktmax_w = (qbase + 31) >> 6;

    STAGE_T(0, 0);
    int cur = 0;

    for (int kt = 0; kt < nt; kt++) {
        // top barrier: (a) staging of buf[cur] complete (compiler drains vmcnt),
        //              (b) all waves done computing from buf[cur^1] -> safe to overwrite
        __syncthreads();
        if (kt + 1 < nt) STAGE_T(cur ^ 1, kt + 1);   // loads fly under this tile's compute

        if (kt <= ktmax_w) {
            const char* sKb = (const char*)&sK[cur][0];
            const char* sVb = (const char*)&sV[cur][0];

            // ---- QK^T (swapped): stc[kt4][qt], D[key-sub, q-sub] ----
            f32x4 stc[4][2];
            #pragma unroll
            for (int kt4 = 0; kt4 < 4; kt4++)
                #pragma unroll
                for (int qt = 0; qt < 2; qt++) stc[kt4][qt] = (f32x4){0.f, 0.f, 0.f, 0.f};
            __builtin_amdgcn_s_setprio(1);
            #pragma unroll
            for (int ks = 0; ks < 4; ks++) {
                #pragma unroll
                for (int kt4 = 0; kt4 < 4; kt4++) {
                    int key = kt4 * 16 + l15;
                    half8 kf = *(const half8*)(sKb + key * 256 + ((ks * 64 + g4 * 16) ^ l7x));
                    stc[kt4][0] = __builtin_amdgcn_mfma_f32_16x16x32_f16(kf, qfrag[0][ks], stc[kt4][0], 0, 0, 0);
                    stc[kt4][1] = __builtin_amdgcn_mfma_f32_16x16x32_f16(kf, qfrag[1][ks], stc[kt4][1], 0, 0, 0);
                }
            }
            __builtin_amdgcn_s_setprio(0);

            // ---- softmax per q-subtile ----
            #pragma unroll
            for (int qt = 0; qt < 2; qt++) {
                int q = qbase + qt * 16 + l15;
                float sv[16];
                #pragma unroll
                for (int kt4 = 0; kt4 < 4; kt4++)
                    #pragma unroll
                    for (int r = 0; r < 4; r++) {
                        int keyg = kt * 64 + kt4 * 16 + 4 * g4 + r;
                        sv[kt4 * 4 + r] = (keyg <= q) ? stc[kt4][qt][r] : -INFINITY;
                    }
                float tmax = sv[0];
                #pragma unroll
                for (int i = 1; i < 16; i++) tmax = fmaxf(tmax, sv[i]);
                tmax = fmaxf(tmax, __shfl_xor(tmax, 16));
                tmax = fmaxf(tmax, __shfl_xor(tmax, 32));
                float nm = fmaxf(m[qt], tmax);
                float alpha = __expf(m[qt] - nm);   // exp(-inf)=0 on first tile
                float p[16], rsum = 0.f;
                #pragma unroll
                for (int i = 0; i < 16; i++) { p[i] = __expf(sv[i] - nm); rsum += p[i]; }
                rsum += __shfl_xor(rsum, 16);
                rsum += __shfl_xor(rsum, 32);
                lsum[qt] = lsum[qt] * alpha + rsum;
                m[qt] = nm;
                #pragma unroll
                for (int r = 0; r < 4; r++) {
                    float ar = __shfl(alpha, 4 * g4 + r);
                    #pragma unroll
                    for (int dt = 0; dt < 8; dt++) o[qt][dt][r] *= ar;
                }
                // P -> sP (swizzled)
                #pragma unroll
                for (int kt4 = 0; kt4 < 4; kt4++)
                    #pragma unroll
                    for (int rp = 0; rp < 4; rp += 2) {
                        half2_t hp;
                        hp[0] = (_Float16)p[kt4 * 4 + rp];
                        hp[1] = (_Float16)p[kt4 * 4 + rp + 1];
                        *(half2_t*)(sPb + (qt * 16 + l15) * 128 +
                                    ((kt4 * 32 + g4 * 8 + rp * 2) ^ l7x)) = hp;
                    }
            }
            asm volatile("s_waitcnt lgkmcnt(0)" ::: "memory");
            __builtin_amdgcn_sched_barrier(0);

            // ---- PV: O[q][d] += P * V ----
            __builtin_amdgcn_s_setprio(1);
            #pragma unroll
            for (int ks = 0; ks < 2; ks++) {
                half8 pf0 = *(const half8*)(sPb + l15 * 128 + ((ks * 64 + g4 * 16) ^ l7x));
                half8 pf1 = *(const half8*)(sPb + (16 + l15) * 128 + ((ks * 64 + g4 * 16) ^ l7x));
                #pragma unroll
                for (int dt = 0; dt < 8; dt++) {
                    int d = dt * 16 + l15;
                    half8 vfr = *(const half8*)(sVb + d * 128 + ((ks * 64 + g4 * 16) ^ l7x));
                    o[0][dt] = __builtin_amdgcn_mfma_f32_16x16x32_f16(pf0, vfr, o[0][dt], 0, 0, 0);
                    o[1][dt] = __builtin_amdgcn_mfma_f32_16x16x32_f16(pf1, vfr, o[1][dt], 0, 0, 0);
                }
            }
            __builtin_amdgcn_s_setprio(0);
        }
        cur ^= 1;
    }
    #undef STAGE_T

    // epilogue: O q-sub = 4*g4 + r (per qt); 1/lsum lives at lane l15 = q-sub
    #pragma unroll
    for (int qt = 0; qt < 2; qt++) {
        float invl = 1.0f / lsum[qt];
        #pragma unroll
        for (int r = 0; r < 4; r++) {
            float ir = __shfl(invl, 4 * g4 + r);
            _Float16* orow = ctx + (size_t)(b * T_ + qbase + qt * 16 + 4 * g4 + r) * (H_ * HD_) + h * HD_ + l15;
            #pragma unroll
            for (int dt = 0; dt < 8; dt++) orow[dt * 16] = (_Float16)(o[qt][dt][r] * ir);
        }
    }
}

// ---------------- launch ----------------
extern "C" void kernel_launch(void* const* d_in, const int* in_sizes, int n_in,
                              void* d_out, int out_size, void* d_ws, size_t ws_size,
                              hipStream_t stream) {
    const float* x   = (const float*)d_in[0];
    const float* Wq  = (const float*)d_in[1];
    const float* Wk  = (const float*)d_in[2];
    const float* Wv  = (const float*)d_in[3];
    const float* Wo  = (const float*)d_in[4];
    const float* qnw = (const float*)d_in[5];
    const float* knw = (const float*)d_in[6];
    float* out = (float*)d_out;

    char* ws = (char*)d_ws;
    size_t off = 0;
    auto alloc = [&](size_t bytes) {
        char* p = ws + off;
        off += (bytes + 255) & ~(size_t)255;
        return p;
    };
    _Float16* x_h  = (_Float16*)alloc((size_t)B_ * T_ * D_ * 2);        // also reused as q_h
    _Float16* wq_h = (_Float16*)alloc((size_t)H_ * HD_ * D_ * 2);       // also reused as kimg+vimg
    _Float16* wk_h = (_Float16*)alloc((size_t)G_ * HD_ * D_ * 2);
    _Float16* wv_h = (_Float16*)alloc((size_t)G_ * HD_ * D_ * 2);
    _Float16* wo_h = (_Float16*)alloc((size_t)D_ * H_ * HD_ * 2);
    float* q_f = (float*)alloc((size_t)B_ * T_ * H_ * HD_ * 4);
    float* k_f = (float*)alloc((size_t)B_ * T_ * G_ * HD_ * 4);
    float* v_f = (float*)alloc((size_t)B_ * T_ * G_ * HD_ * 4);
    _Float16* ctx_h = (_Float16*)alloc((size_t)B_ * T_ * H_ * HD_ * 2);
    float* cosT = (float*)alloc((size_t)T_ * 64 * 4);
    float* sinT = (float*)alloc((size_t)T_ * 64 * 4);

    // aliases (lifetimes disjoint with originals):
    _Float16* q_h  = x_h;                       // x_h dead after QKV GEMM
    _Float16* kimg = wq_h;                      // wq_h dead after QKV GEMM; kimg 4 MB
    _Float16* vimg = wq_h + (size_t)2 * 4 * 32 * 8192;  // next 4 MB of wq_h

    // dtype conversions
    cvt_f16<<<2048, 256, 0, stream>>>(x,  x_h,  B_ * T_ * D_);
    cvt_f16<<<2048, 256, 0, stream>>>(Wq, wq_h, H_ * HD_ * D_);
    cvt_f16<<<1024, 256, 0, stream>>>(Wk, wk_h, G_ * HD_ * D_);
    cvt_f16<<<1024, 256, 0, stream>>>(Wv, wv_h, G_ * HD_ * D_);
    cvt_f16<<<2048, 256, 0, stream>>>(Wo, wo_h, D_ * H_ * HD_);
    rope_tables_k<<<(T_ * 64) / 256, 256, 0, stream>>>(cosT, sinT);

    // fused Q+K+V projection: one dispatch, 768 blocks (3/CU)
    gemm_tile<<<dim3(32, 24), 256, 0, stream>>>(x_h, wq_h, q_f, 16,
                                                wk_h, k_f, 4,
                                                wv_h, v_f, 4, D_);

    // norm + rope; Q -> f16 (x_h buffer), score scale 1/128 folded into Q; K in-place f32
    rmsnorm_rope_k<<<(B_ * T_ * H_) / 4, 256, 0, stream>>>(q_f, qnw, cosT, sinT, H_, 1.0f / 128.0f, q_h);
    rmsnorm_rope_k<<<(B_ * T_ * G_) / 4, 256, 0, stream>>>(k_f, knw, cosT, sinT, G_, 1.0f, nullptr);

    // pack K/V into swizzled f16 tile images (reusing wq_h)
    pack_k<<<1024, 256, 0, stream>>>(k_f, kimg);
    pack_v<<<256, 256, 0, stream>>>(v_f, vimg);

    // causal GQA attention -> ctx (f16)
    attn_mfma3<<<512, 256, 0, stream>>>(q_h, kimg, vimg, ctx_h);

    // output projection -> d_out (fp32)
    gemm_tile<<<dim3(32, 16), 256, 0, stream>>>(ctx_h, wo_h, out, 16,
                                                nullptr, nullptr, 0,
                                                nullptr, nullptr, 0, H_ * HD_);
}

// Round 6
// 248.669 us; speedup vs baseline: 8.6853x; 1.2162x over previous
//
#include <hip/hip_runtime.h>
#include <hip/hip_bf16.h>

// Problem constants (match reference)
#define B_ 2
#define T_ 2048
#define D_ 2048
#define H_ 16
#define G_ 4
#define HD_ 128
#define GS_ (H_/G_)

typedef _Float16 half8 __attribute__((ext_vector_type(8)));
typedef _Float16 half2_t __attribute__((ext_vector_type(2)));
typedef float f32x4 __attribute__((ext_vector_type(4)));
typedef float f32x16 __attribute__((ext_vector_type(16)));
typedef int int4_t __attribute__((ext_vector_type(4)));

// Combined KV tile image: per (b,g,tile64): [K: 64 rows x 136 f16 (128 data + 8 pad)]
// then [V^T: 128 rows x 72 f16 (64 data + 8 pad)]. 17408 + 18432 = 35840 bytes.
#define KV_TILE_BYTES 35840
#define KROW_F16 136
#define VROW_F16 72
#define VBASE_F16 8704   // 17408 bytes / 2

// ---------------- fp32 -> fp16 conversion ----------------
__global__ void cvt_f16(const float* __restrict__ in, _Float16* __restrict__ out, int n) {
    int i = blockIdx.x * blockDim.x + threadIdx.x;
    int stride = blockDim.x * gridDim.x;
    for (; i < n; i += stride) out[i] = (_Float16)in[i];
}

// ---------------- RoPE tables: cos/sin (T_, 64) ----------------
__global__ void rope_tables_k(float* __restrict__ cosT, float* __restrict__ sinT) {
    int i = blockIdx.x * blockDim.x + threadIdx.x; // T_*64 threads
    int t = i >> 6, l = i & 63;
    float inv_freq = powf(10000.0f, -((float)(2 * l)) / 128.0f);
    float a = (float)t * inv_freq;
    cosT[i] = cosf(a);
    sinT[i] = sinf(a);
}

// ---------------- Tiled TN GEMM (m97 structure, up to 3 fused outputs) ----------------
__global__ void __launch_bounds__(256) gemm_tile(const _Float16* __restrict__ A,
                                                 const _Float16* __restrict__ B0,
                                                 float* __restrict__ C0, int n0t,
                                                 const _Float16* __restrict__ B1,
                                                 float* __restrict__ C1, int n1t,
                                                 const _Float16* __restrict__ B2,
                                                 float* __restrict__ C2, int n2t,
                                                 int Kd) {
    __shared__ _Float16 sA[128 * 32];
    __shared__ _Float16 sB[128 * 32];

    int tid = threadIdx.x;
    int w = tid >> 6, lane = tid & 63;
    int l15 = lane & 15, g4 = lane >> 4;
    int wm = w >> 1, wn = w & 1;

    int y = blockIdx.y;
    const _Float16* Bsel;
    float* Csel;
    int ldc, cb;
    if (y < n0t)            { Bsel = B0; Csel = C0; ldc = n0t * 128; cb = y; }
    else if (y < n0t + n1t) { Bsel = B1; Csel = C1; ldc = n1t * 128; cb = y - n0t; }
    else                    { Bsel = B2; Csel = C2; ldc = n2t * 128; cb = y - n0t - n1t; }

    const _Float16* Ab = A + (size_t)(blockIdx.x * 128) * Kd;
    const _Float16* Bb = Bsel + (size_t)(cb * 128) * Kd;

    int s0 = w * 128 + lane;
    int s1 = s0 + 64;
    int r0 = s0 >> 2, c0 = s0 & 3;
    int r1 = s1 >> 2, c1 = s1 & 3;
    size_t ga0 = (size_t)r0 * Kd + c0 * 8;
    size_t ga1 = (size_t)r1 * Kd + c1 * 8;
    _Float16* lds_a0 = sA + (size_t)(w * 2) * 512;
    _Float16* lds_a1 = sA + (size_t)(w * 2 + 1) * 512;
    _Float16* lds_b0 = sB + (size_t)(w * 2) * 512;
    _Float16* lds_b1 = sB + (size_t)(w * 2 + 1) * 512;

    #define STAGE(K0)                                                                     \
        do {                                                                              \
            __builtin_amdgcn_global_load_lds(                                             \
                (const __attribute__((address_space(1))) unsigned int*)(Ab + ga0 + (K0)), \
                (__attribute__((address_space(3))) unsigned int*)lds_a0, 16, 0, 0);       \
            __builtin_amdgcn_global_load_lds(                                             \
                (const __attribute__((address_space(1))) unsigned int*)(Ab + ga1 + (K0)), \
                (__attribute__((address_space(3))) unsigned int*)lds_a1, 16, 0, 0);       \
            __builtin_amdgcn_global_load_lds(                                             \
                (const __attribute__((address_space(1))) unsigned int*)(Bb + ga0 + (K0)), \
                (__attribute__((address_space(3))) unsigned int*)lds_b0, 16, 0, 0);       \
            __builtin_amdgcn_global_load_lds(                                             \
                (const __attribute__((address_space(1))) unsigned int*)(Bb + ga1 + (K0)), \
                (__attribute__((address_space(3))) unsigned int*)lds_b1, 16, 0, 0);       \
        } while (0)

    f32x4 acc[4][4];
    #pragma unroll
    for (int i = 0; i < 4; i++)
        #pragma unroll
        for (int j = 0; j < 4; j++) acc[i][j] = (f32x4){0.f, 0.f, 0.f, 0.f};

    STAGE(0);

    int nIt = Kd >> 5;
    for (int it = 0; it < nIt; ++it) {
        __syncthreads();

        half8 af[4], bf[4];
        #pragma unroll
        for (int mi = 0; mi < 4; mi++)
            af[mi] = *(const half8*)&sA[(wm * 64 + mi * 16 + l15) * 32 + g4 * 8];
        #pragma unroll
        for (int ni = 0; ni < 4; ni++)
            bf[ni] = *(const half8*)&sB[(wn * 64 + ni * 16 + l15) * 32 + g4 * 8];

        #pragma unroll
        for (int mi = 0; mi < 4; mi++)
            #pragma unroll
            for (int ni = 0; ni < 4; ni++)
                acc[mi][ni] = __builtin_amdgcn_mfma_f32_16x16x32_f16(af[mi], bf[ni], acc[mi][ni], 0, 0, 0);

        if (it + 1 < nIt) {
            __syncthreads();
            STAGE((size_t)(it + 1) * 32);
        }
    }
    #undef STAGE

    int rbase = blockIdx.x * 128 + wm * 64 + g4 * 4;
    int cbase = cb * 128 + wn * 64 + l15;
    #pragma unroll
    for (int mi = 0; mi < 4; mi++)
        #pragma unroll
        for (int r = 0; r < 4; r++) {
            float* crow = Csel + (size_t)(rbase + mi * 16 + r) * ldc + cbase;
            #pragma unroll
            for (int ni = 0; ni < 4; ni++) crow[ni * 16] = acc[mi][ni][r];
        }
}

// ---------------- fused RMSNorm + RoPE ----------------
__global__ void rmsnorm_rope_k(float* __restrict__ X, const float* __restrict__ w,
                               const float* __restrict__ cosT, const float* __restrict__ sinT,
                               int heads, float outScale, _Float16* __restrict__ outH) {
    int gw = (int)((blockIdx.x * (size_t)blockDim.x + threadIdx.x) >> 6);
    int lane = threadIdx.x & 63;
    float* row = X + (size_t)gw * HD_;
    int t = (gw / heads) % T_;   // row index = (b*T + t)*heads + h
    float x0 = row[lane];
    float x1 = row[lane + 64];
    float ss = x0 * x0 + x1 * x1;
    #pragma unroll
    for (int off = 1; off < 64; off <<= 1) ss += __shfl_xor(ss, off);
    float inv = rsqrtf(ss * (1.0f / 128.0f) + 1e-6f);
    float n0 = x0 * inv * w[lane];
    float n1 = x1 * inv * w[lane + 64];
    float c = cosT[t * 64 + lane];
    float s = sinT[t * 64 + lane];
    float r0 = (n0 * c - n1 * s) * outScale;
    float r1 = (n1 * c + n0 * s) * outScale;
    if (outH) {
        outH[(size_t)gw * HD_ + lane]      = (_Float16)r0;
        outH[(size_t)gw * HD_ + lane + 64] = (_Float16)r1;
    } else {
        row[lane]      = r0;
        row[lane + 64] = r1;
    }
}

// ---------------- pack K+V into combined padded f16 tile image ----------------
// Grid: 256 blocks = (b,g,tile64); 256 threads.
__global__ void __launch_bounds__(256) pack_kv(const float* __restrict__ kf,
                                               const float* __restrict__ vf,
                                               _Float16* __restrict__ img) {
    int bid = blockIdx.x;
    int tile = bid & 31, g = (bid >> 5) & 3, b = bid >> 7;
    int tid = threadIdx.x;
    _Float16* out = img + (size_t)bid * (KV_TILE_BYTES / 2);

    // K part: 64 rows x 17 granules (granule 16 = pad)
    #pragma unroll
    for (int it = 0; it < 5; it++) {
        int gi = tid + 256 * it;
        if (gi < 64 * 17) {
            int key = gi / 17, gr = gi % 17;
            half8 hv = (half8){0, 0, 0, 0, 0, 0, 0, 0};
            if (gr < 16) {
                const float* src = kf + ((size_t)((b * T_ + tile * 64 + key) * G_ + g)) * HD_ + gr * 8;
                #pragma unroll
                for (int j = 0; j < 8; j++) hv[j] = (_Float16)src[j];
            }
            *(half8*)(out + (size_t)gi * 8) = hv;
        }
    }
    // V^T part: 128 rows (d) x 9 granules (granule 8 = pad); strided gather transpose
    #pragma unroll
    for (int it = 0; it < 5; it++) {
        int vi = tid + 256 * it;
        if (vi < 128 * 9) {
            int d = vi / 9, gr = vi % 9;
            half8 hv = (half8){0, 0, 0, 0, 0, 0, 0, 0};
            if (gr < 8) {
                const float* src = vf + ((size_t)((b * T_ + tile * 64 + gr * 8) * G_ + g)) * HD_ + d;
                #pragma unroll
                for (int j = 0; j < 8; j++) hv[j] = (_Float16)src[(size_t)j * (G_ * HD_)];
            }
            *(half8*)(out + VBASE_F16 + (size_t)vi * 8) = hv;
        }
    }
}

// ---------------- causal GQA flash attention v4 ----------------
// 32x32x16 MFMA, swapped QK^T, fully in-register softmax + P (T12), defer-max (T13).
// Block: 4 waves x 32 q-rows = 128 q-rows, one head. KV tiles of 64 keys,
// double-buffered combined K/V LDS record (2 x 35 KB), linear global_load_lds staging.
__global__ void __launch_bounds__(256, 2) attn_mfma4(const _Float16* __restrict__ qh,
                                                     const _Float16* __restrict__ kvimg,
                                                     _Float16* __restrict__ ctx) {
    // balanced grid decode: pair (qb, 15-qb) across grid halves
    int id = blockIdx.x;
    int hlf = id >> 8, rr0 = id & 255;
    int qb = hlf ? (15 - (rr0 & 15)) : (rr0 & 15);
    int hb = (rr0 >> 4) | (hlf << 4);
    int h = hb & 15, b = hb >> 4;
    int g = h >> 2;

    int tid = threadIdx.x;
    int w = tid >> 6, lane = tid & 63;
    int l31 = lane & 31, hi = lane >> 5;

    __shared__ __align__(16) char sKV[2][KV_TILE_BYTES];

    int qW = qb * 128 + w * 32;
    int qme = qW + l31;

    // Q B-frags: qfrag[ks] = Q[qme][ks*16 + hi*8 + j]
    half8 qfrag[8];
    {
        const _Float16* qrow = qh + ((size_t)(b * T_ + qme)) * (H_ * HD_) + h * HD_ + hi * 8;
        #pragma unroll
        for (int ks = 0; ks < 8; ks++) qfrag[ks] = *(const half8*)(qrow + ks * 16);
    }

    f32x16 o[4];
    #pragma unroll
    for (int dt2 = 0; dt2 < 4; dt2++)
        #pragma unroll
        for (int r = 0; r < 16; r++) o[dt2][r] = 0.f;
    float m = -INFINITY, lsum = 0.f;

    const char* ibase = (const char*)kvimg + (size_t)((b * 4 + g) * 32) * KV_TILE_BYTES;

    #define STAGE_T(BUF, KT)                                                                       \
        do {                                                                                       \
            const char* src_ = ibase + (size_t)(KT) * KV_TILE_BYTES;                               \
            char* dst_ = &sKV[BUF][0];                                                             \
            _Pragma("unroll")                                                                      \
            for (int i_ = 0; i_ < 9; i_++) {                                                       \
                int c_ = w + 4 * i_;                                                               \
                if (c_ < 35) {                                                                     \
                    __builtin_amdgcn_global_load_lds(                                              \
                        (const __attribute__((address_space(1))) unsigned int*)(src_ + c_ * 1024 + lane * 16), \
                        (__attribute__((address_space(3))) unsigned int*)(dst_ + c_ * 1024 + lane * 16), 16, 0, 0); \
                }                                                                                  \
            }                                                                                      \
        } while (0)

    int nt = 2 * qb + 2;
    int ktmax_w = (qW + 31) >> 6;

    STAGE_T(0, 0);
    int cur = 0;

    for (int kt = 0; kt < nt; kt++) {
        // top barrier: buf[cur] staged (vmcnt drained) AND previous compute done
        __syncthreads();
        if (kt + 1 < nt) STAGE_T(cur ^ 1, kt + 1);

        if (kt <= ktmax_w) {
            const char* bufK = &sKV[cur][0];
            const char* bufV = &sKV[cur][0] + VBASE_F16 * 2;

            // ---- swapped QK^T: stc[kt2] = S^T, col = q (l31), rows = 32 keys ----
            f32x16 stc[2];
            #pragma unroll
            for (int kt2 = 0; kt2 < 2; kt2++)
                #pragma unroll
                for (int r = 0; r < 16; r++) stc[kt2][r] = 0.f;

            __builtin_amdgcn_s_setprio(1);
            #pragma unroll
            for (int ks = 0; ks < 8; ks++) {
                #pragma unroll
                for (int kt2 = 0; kt2 < 2; kt2++) {
                    half8 kfr = *(const half8*)(bufK + (kt2 * 32 + l31) * (KROW_F16 * 2) + ks * 32 + hi * 16);
                    stc[kt2] = __builtin_amdgcn_mfma_f32_32x32x16_f16(kfr, qfrag[ks], stc[kt2], 0, 0, 0);
                }
            }
            __builtin_amdgcn_s_setprio(0);

            // ---- causal mask (in place) ----
            #pragma unroll
            for (int kt2 = 0; kt2 < 2; kt2++)
                #pragma unroll
                for (int reg = 0; reg < 16; reg++) {
                    int key = kt * 64 + kt2 * 32 + 8 * (reg >> 2) + 4 * hi + (reg & 3);
                    float v = stc[kt2][reg];
                    stc[kt2][reg] = (key <= qme) ? v : -INFINITY;
                }

            // ---- in-lane max + defer-max rescale (T13) ----
            float pmax = -INFINITY;
            #pragma unroll
            for (int kt2 = 0; kt2 < 2; kt2++)
                #pragma unroll
                for (int reg = 0; reg < 16; reg++) pmax = fmaxf(pmax, stc[kt2][reg]);
            pmax = fmaxf(pmax, __shfl_xor(pmax, 32));

            if (__any(!(pmax - m <= 8.0f))) {
                float nm = fmaxf(m, pmax);
                float alpha = __expf(m - nm);   // first tile: exp(-inf)=0
                lsum *= alpha;
                #pragma unroll
                for (int reg = 0; reg < 16; reg++) {
                    float ar = __shfl(alpha, 8 * (reg >> 2) + 4 * hi + (reg & 3));
                    #pragma unroll
                    for (int dt2 = 0; dt2 < 4; dt2++) o[dt2][reg] *= ar;
                }
                m = nm;
            }

            // ---- exp + row-sum (in place) ----
            float rsum = 0.f;
            #pragma unroll
            for (int kt2 = 0; kt2 < 2; kt2++)
                #pragma unroll
                for (int reg = 0; reg < 16; reg++) {
                    float e = __expf(stc[kt2][reg] - m);
                    stc[kt2][reg] = e;
                    rsum += e;
                }
            rsum += __shfl_xor(rsum, 32);
            lsum += rsum;

            // ---- pack P to f16 dwords: pk[kt2*8 + 2*o + c] = keys (8o+4hi+2c, +1) ----
            int pk[16];
            #pragma unroll
            for (int kt2 = 0; kt2 < 2; kt2++)
                #pragma unroll
                for (int oo = 0; oo < 4; oo++)
                    #pragma unroll
                    for (int c = 0; c < 2; c++) {
                        half2_t hp;
                        hp[0] = (_Float16)stc[kt2][4 * oo + 2 * c];
                        hp[1] = (_Float16)stc[kt2][4 * oo + 2 * c + 1];
                        pk[kt2 * 8 + 2 * oo + c] = __builtin_bit_cast(int, hp);
                    }

            // ---- PV: for each 16-key step, assemble P A-frag in-register, MFMA with V ----
            __builtin_amdgcn_s_setprio(1);
            #pragma unroll
            for (int ks = 0; ks < 4; ks++) {
                int base = (ks >> 1) * 8 + (ks & 1) * 4;
                int z0 = hi ? pk[base + 0] : pk[base + 2];
                int z1 = hi ? pk[base + 1] : pk[base + 3];
                int xz0 = __shfl_xor(z0, 32);
                int xz1 = __shfl_xor(z1, 32);
                int4_t pi;
                pi[0] = hi ? xz0 : pk[base + 0];
                pi[1] = hi ? xz1 : pk[base + 1];
                pi[2] = hi ? pk[base + 2] : xz0;
                pi[3] = hi ? pk[base + 3] : xz1;
                half8 pfrag = __builtin_bit_cast(half8, pi);
                #pragma unroll
                for (int dt2 = 0; dt2 < 4; dt2++) {
                    half8 vfr = *(const half8*)(bufV + (dt2 * 32 + l31) * (VROW_F16 * 2) + ks * 32 + hi * 16);
                    o[dt2] = __builtin_amdgcn_mfma_f32_32x32x16_f16(pfrag, vfr, o[dt2], 0, 0, 0);
                }
            }
            __builtin_amdgcn_s_setprio(0);
        }
        cur ^= 1;
    }
    #undef STAGE_T

    // ---- epilogue: O rows = q(reg) = 8*(reg>>2)+4*hi+(reg&3), col = d = dt2*32 + l31 ----
    float invl = 1.0f / lsum;
    #pragma unroll
    for (int reg = 0; reg < 16; reg++) {
        int qrow = 8 * (reg >> 2) + 4 * hi + (reg & 3);
        float ir = __shfl(invl, qrow);
        _Float16* orow = ctx + (size_t)(b * T_ + qW + qrow) * (H_ * HD_) + h * HD_ + l31;
        #pragma unroll
        for (int dt2 = 0; dt2 < 4; dt2++)
            orow[dt2 * 32] = (_Float16)(o[dt2][reg] * ir);
    }
}

// ---------------- launch ----------------
extern "C" void kernel_launch(void* const* d_in, const int* in_sizes, int n_in,
                              void* d_out, int out_size, void* d_ws, size_t ws_size,
                              hipStream_t stream) {
    const float* x   = (const float*)d_in[0];
    const float* Wq  = (const float*)d_in[1];
    const float* Wk  = (const float*)d_in[2];
    const float* Wv  = (const float*)d_in[3];
    const float* Wo  = (const float*)d_in[4];
    const float* qnw = (const float*)d_in[5];
    const float* knw = (const float*)d_in[6];
    float* out = (float*)d_out;

    char* ws = (char*)d_ws;
    size_t off = 0;
    auto alloc = [&](size_t bytes) {
        char* p = ws + off;
        off += (bytes + 255) & ~(size_t)255;
        return p;
    };
    _Float16* x_h  = (_Float16*)alloc((size_t)B_ * T_ * D_ * 2);        // reused as q_h
    _Float16* wq_h = (_Float16*)alloc((size_t)H_ * HD_ * D_ * 2);       // reused as kvimg (with wk_h)
    _Float16* wk_h = (_Float16*)alloc((size_t)G_ * HD_ * D_ * 2);
    _Float16* wv_h = (_Float16*)alloc((size_t)G_ * HD_ * D_ * 2);
    _Float16* wo_h = (_Float16*)alloc((size_t)D_ * H_ * HD_ * 2);
    float* q_f = (float*)alloc((size_t)B_ * T_ * H_ * HD_ * 4);
    float* k_f = (float*)alloc((size_t)B_ * T_ * G_ * HD_ * 4);
    float* v_f = (float*)alloc((size_t)B_ * T_ * G_ * HD_ * 4);
    _Float16* ctx_h = (_Float16*)alloc((size_t)B_ * T_ * H_ * HD_ * 2);
    float* cosT = (float*)alloc((size_t)T_ * 64 * 4);
    float* sinT = (float*)alloc((size_t)T_ * 64 * 4);

    // aliases (lifetimes disjoint):
    _Float16* q_h   = x_h;     // x_h dead after QKV GEMM
    _Float16* kvimg = wq_h;    // wq_h+wk_h dead after QKV GEMM; image = 256*35840 = 9.2 MB

    // dtype conversions
    cvt_f16<<<2048, 256, 0, stream>>>(x,  x_h,  B_ * T_ * D_);
    cvt_f16<<<2048, 256, 0, stream>>>(Wq, wq_h, H_ * HD_ * D_);
    cvt_f16<<<1024, 256, 0, stream>>>(Wk, wk_h, G_ * HD_ * D_);
    cvt_f16<<<1024, 256, 0, stream>>>(Wv, wv_h, G_ * HD_ * D_);
    cvt_f16<<<2048, 256, 0, stream>>>(Wo, wo_h, D_ * H_ * HD_);
    rope_tables_k<<<(T_ * 64) / 256, 256, 0, stream>>>(cosT, sinT);

    // fused Q+K+V projection
    gemm_tile<<<dim3(32, 24), 256, 0, stream>>>(x_h, wq_h, q_f, 16,
                                                wk_h, k_f, 4,
                                                wv_h, v_f, 4, D_);

    // norm + rope; Q -> f16 (x_h buffer), score scale 1/128 folded into Q; K in-place f32
    rmsnorm_rope_k<<<(B_ * T_ * H_) / 4, 256, 0, stream>>>(q_f, qnw, cosT, sinT, H_, 1.0f / 128.0f, q_h);
    rmsnorm_rope_k<<<(B_ * T_ * G_) / 4, 256, 0, stream>>>(k_f, knw, cosT, sinT, G_, 1.0f, nullptr);

    // pack K/V into combined padded f16 tile images
    pack_kv<<<256, 256, 0, stream>>>(k_f, v_f, kvimg);

    // causal GQA attention -> ctx (f16)
    attn_mfma4<<<512, 256, 0, stream>>>(q_h, kvimg, ctx_h);

    // output projection -> d_out (fp32)
    gemm_tile<<<dim3(32, 16), 256, 0, stream>>>(ctx_h, wo_h, out, 16,
                                                nullptr, nullptr, 0,
                                                nullptr, nullptr, 0, H_ * HD_);
}